// Round 6
// baseline (343.632 us; speedup 1.0000x reference)
//
#include <hip/hip_runtime.h>
#include <cmath>

#define NB 16
#define TAILV 3.0f
#define MINV 0.001f
#define CSC 0.984f   // 1 - NB*MINV

typedef __attribute__((ext_vector_type(8))) _Float16 half8;
typedef __attribute__((ext_vector_type(4))) float f32x4;

#define MFMA16(a,b,c) __builtin_amdgcn_mfma_f32_16x16x32_f16(a,b,c,0,0,0)

__device__ __forceinline__ ushort f2h(float f) {
    union { _Float16 h; ushort u; } v; v.h = (_Float16)f; return v.u;
}
__device__ __forceinline__ float h2f(ushort u) {
    union { ushort u; _Float16 h; } v; v.u = u; return (float)v.h;
}
__device__ __forceinline__ float softplus_f(float x) {
    return (x > 20.0f) ? x : __logf(1.0f + __expf(x));   // fast-math: margin absorbs ~ulp error
}

// ---- prologue: convert/transpose weights into d_ws (fp16, [N][K]) ----
// W3T: [2048][256], n = dim*64 + p (p<49 real, else 0).  W2T: [256][256].  W1T: [256][32].
__global__ void __launch_bounds__(256)
cvt_weights(const float* __restrict__ W1, const float* __restrict__ W2,
            const float* __restrict__ W3, const float* __restrict__ b3,
            ushort* __restrict__ W3T, ushort* __restrict__ W2T,
            ushort* __restrict__ W1T, float* __restrict__ b3p)
{
    __shared__ float sm[64][65];
    const int b = blockIdx.x, t = threadIdx.x;
    const int tx = t & 63, ty = t >> 6;

    if (b < 100) {
        const int kt = b / 25, ct = b % 25;
        const int c = ct * 64 + tx;
        #pragma unroll
        for (int i = 0; i < 16; ++i) {
            const int k = kt * 64 + ty * 16 + i;
            float v = (c < 1568) ? W3[(size_t)k * 1568 + c] : 0.0f;
            sm[tx][ty * 16 + i] = v;               // sm[c_local][k_local]
        }
        __syncthreads();
        #pragma unroll
        for (int i = 0; i < 16; ++i) {
            const int clocal = ty * 16 + i;
            const int cc = ct * 64 + clocal;
            if (cc < 1568) {
                const int dim = cc / 49;
                const int p   = cc - dim * 49;
                const int n   = dim * 64 + p;
                W3T[(size_t)n * 256 + kt * 64 + tx] = f2h(sm[clocal][tx]);
            }
        }
    } else if (b < 580) {        // zero pad rows: n = dim*64 + 49 + q
        const int z = b - 100;
        const int dim = z / 15, q = z - dim * 15;
        const int n = dim * 64 + 49 + q;
        W3T[(size_t)n * 256 + t] = 0;
    } else if (b < 588) {        // b3p
        const int n = (b - 580) * 256 + t;
        const int dim = n >> 6, p = n & 63;
        b3p[n] = (p < 49) ? b3[dim * 49 + p] : 0.0f;
    } else if (b < 844) {        // W2T
        const int n = b - 588;
        W2T[(size_t)n * 256 + t] = f2h(W2[(size_t)t * 256 + n]);
    } else {                     // W1T (32 blocks, 8192 elems)
        const int idx = (b - 844) * 256 + t;
        const int n = idx >> 5, k = idx & 31;
        W1T[idx] = f2h(W1[(size_t)k * 256 + n]);
    }
}

// ---- fused main kernel: 32 batch rows / block, 4 waves, 2048 blocks ----
// Occupancy-first restructure: LDS 39168 B and phase-4 live regs ~150
// (A[2][8]=64, b[8]=32, no software B-prefetch, single fp16 P buffer)
// -> target 3-4 blocks/CU (12-16 waves/CU) vs previous 2 blocks (8 waves).
// The extra waves/SIMD hide the spline's serial chains and the per-nt-tile
// B-load latency (W3T is L2-resident).
// Phase 4 processes dims in SUPER-CHUNKS of 2 so the spline fills all 64
// lanes: lane = (row 0-31) x (dim-pair j 0/1).
extern "C" __global__ void __launch_bounds__(256, 3)
rq_mfma(const float* __restrict__ x1, const float* __restrict__ x2,
        const float* __restrict__ b1, const float* __restrict__ b2,
        const ushort* __restrict__ W1T, const ushort* __restrict__ W2T,
        const ushort* __restrict__ W3T, const float* __restrict__ b3p,
        float* __restrict__ zout, float* __restrict__ ldout)
{
    __shared__ char smem[39168];
    float*  sX2  = (float*)smem;                    // [32][33] f32 = 4224
    float*  sLDw = (float*)(smem + 4224);           // [32][9] f32 = 1152
    char*   U    = smem + 5376;                     // 33792-byte union
    ushort* R0   = (ushort*)U;                      // [32][264] fp16 = 16896 (h1)
    ushort* R1   = (ushort*)(U + 16896);            // [32][264] fp16 = 16896 (h2)
    ushort* sA1  = R1;                              // [32][40] fp16 overlay (x1)
    ushort* sP   = (ushort*)U;                      // 4w x 2dim x [32][50] fp16 = 25600 overlay

    const int tid  = threadIdx.x;
    const int row0 = blockIdx.x * 32;
    const int rot  = blockIdx.x & 7;
    const int wave = tid >> 6, lane = tid & 63;
    const int ln = lane & 15, kg = lane >> 4;       // frag: m/n=ln, k-group=kg

    // ---- phase 0: stage x1 (->fp16, sA1 overlay on R1) and x2 (f32) ----
    {
        int r = tid >> 3, c = (tid & 7) << 2;
        float4 v = *(const float4*)(x1 + (size_t)(row0 + r) * 32 + c);
        sA1[r*40 + c    ] = f2h(v.x); sA1[r*40 + c + 1] = f2h(v.y);
        sA1[r*40 + c + 2] = f2h(v.z); sA1[r*40 + c + 3] = f2h(v.w);
        float4 w = *(const float4*)(x2 + (size_t)(row0 + r) * 32 + c);
        sX2[r*33 + c    ] = w.x; sX2[r*33 + c + 1] = w.y;
        sX2[r*33 + c + 2] = w.z; sX2[r*33 + c + 3] = w.w;
    }
    __syncthreads();

    // ---- phase 1: h1 = relu(x1 @ W1 + b1); 2 M-tiles, K=32; -> R0 ----
    {
        half8 a[2];
        #pragma unroll
        for (int m = 0; m < 2; ++m)
            a[m] = *(const half8*)(sA1 + (m*16 + ln)*40 + kg*8);
        #pragma unroll
        for (int nt = 0; nt < 4; ++nt) {
            int n = wave*64 + nt*16 + ln;
            half8 bfr = *(const half8*)(W1T + n*32 + kg*8);
            float bias = b1[n];
            f32x4 zr = {0.f,0.f,0.f,0.f};
            #pragma unroll
            for (int m = 0; m < 2; ++m) {
                f32x4 cm = MFMA16(a[m], bfr, zr);
                #pragma unroll
                for (int g = 0; g < 4; ++g)
                    R0[(m*16 + kg*4 + g)*264 + n] = f2h(fmaxf(cm[g] + bias, 0.f));
            }
        }
    }
    __syncthreads();   // sA1 (R1 overlay) now dead

    // ---- phase 2: h2 = relu(h1 @ W2 + b2); R0 -> R1 ----
    {
        half8 a0[8], a1[8];
        #pragma unroll
        for (int ks = 0; ks < 8; ++ks) {
            a0[ks] = *(const half8*)(R0 + ln*264 + ks*32 + kg*8);
            a1[ks] = *(const half8*)(R0 + (16 + ln)*264 + ks*32 + kg*8);
        }
        #pragma unroll
        for (int nt = 0; nt < 4; ++nt) {
            int n = wave*64 + nt*16 + ln;
            f32x4 c0 = {0,0,0,0}, c1 = {0,0,0,0};
            const ushort* bp = W2T + (size_t)n*256 + kg*8;
            #pragma unroll
            for (int ks = 0; ks < 8; ++ks) {
                half8 bfr = *(const half8*)(bp + ks*32);
                c0 = MFMA16(a0[ks], bfr, c0);
                c1 = MFMA16(a1[ks], bfr, c1);
            }
            float bias = b2[n];
            #pragma unroll
            for (int g = 0; g < 4; ++g) {
                R1[(kg*4 + g)*264 + n]      = f2h(fmaxf(c0[g] + bias, 0.f));
                R1[(16 + kg*4 + g)*264 + n] = f2h(fmaxf(c1[g] + bias, 0.f));
            }
        }
        __syncthreads();
    }

    // ---- phase 3: hoist GEMM3 A-fragments (2 M-tiles x 8 ks = 64 regs) ----
    half8 A[2][8];
    #pragma unroll
    for (int m = 0; m < 2; ++m)
        #pragma unroll
        for (int ks = 0; ks < 8; ++ks)
            A[m][ks] = *(const half8*)(R1 + (m*16 + ln)*264 + ks*32 + kg*8);
    __syncthreads();   // staging dead; sP overlays U

    // ---- phase 4: GEMM3 + fused spline; wave owns dims [wave*8, wave*8+8) ----
    // 4 super-chunks x 2 dims; single fp16 P buffer per wave (in-order
    // same-wave write->read, no barrier needed; HW-validated r0/r2/r5).
    ushort* myP = sP + wave * 3200;                // 2 x [32][50] fp16
    float   ldacc = 0.f;

    for (int sc = 0; sc < 4; ++sc) {
        #pragma unroll
        for (int j2 = 0; j2 < 2; ++j2) {
            const int dim = wave*8 + ((sc*2 + j2 + rot) & 7);
            ushort* P = myP + j2*1600;
            float bias[4];
            #pragma unroll
            for (int nt = 0; nt < 4; ++nt) bias[nt] = b3p[dim*64 + nt*16 + ln];

            #pragma unroll
            for (int nt = 0; nt < 4; ++nt) {
                const ushort* bp = W3T + (size_t)(dim*64 + nt*16 + ln)*256 + kg*8;
                half8 bfr[8];
                #pragma unroll
                for (int ks = 0; ks < 8; ++ks) bfr[ks] = *(const half8*)(bp + ks*32);
                f32x4 c0 = {0,0,0,0}, c1 = {0,0,0,0};
                #pragma unroll
                for (int ks = 0; ks < 8; ++ks) {
                    c0 = MFMA16(A[0][ks], bfr[ks], c0);
                    c1 = MFMA16(A[1][ks], bfr[ks], c1);
                }
                int p = nt*16 + ln;
                if (p < 49) {
                    #pragma unroll
                    for (int g = 0; g < 4; ++g) {
                        P[(kg*4 + g)*50 + p]      = f2h(c0[g] + bias[nt]);
                        P[(16 + kg*4 + g)*50 + p] = f2h(c1[g] + bias[nt]);
                    }
                }
            }
        }

        // spline: 2 dims x 32 rows = 64 tasks = 1/lane (r=lane&31, j=lane>>5)
        // body identical to r5-verified version (no-max softmax, fused log)
        {
            const int r   = lane & 31, j = lane >> 5;
            const int dim = wave*8 + ((sc*2 + j + rot) & 7);
            const ushort* pp = myP + j*1600 + r*50;
            const float x  = sX2[r*33 + dim];
            const float xc = fminf(fmaxf(x, -TAILV), TAILV);

            float e[NB]; float s = 0.f;
            #pragma unroll
            for (int k = 0; k < NB; ++k) { e[k] = __expf(h2f(pp[k])); s += e[k]; }
            const float inv = 1.f / s;

            int idx = 0; float xk = -TAILV, xk1 = TAILV; float cum = 0.f;
            #pragma unroll
            for (int k = 0; k < NB; ++k) {
                float lo = -TAILV + 2.f * TAILV * cum;
                cum += MINV + CSC * e[k] * inv;
                float hi = -TAILV + 2.f * TAILV * cum;
                if (lo <= xc) { idx = k; xk = lo; xk1 = hi; }
            }

            float eh[NB]; float sh = 0.f;
            #pragma unroll
            for (int k = 0; k < NB; ++k) { eh[k] = __expf(h2f(pp[NB + k])); sh += eh[k]; }
            const float invh = 1.f / sh;

            float yk = -TAILV, yk1 = TAILV; cum = 0.f;
            #pragma unroll
            for (int k = 0; k < NB; ++k) {
                float lo = -TAILV + 2.f * TAILV * cum;
                cum += MINV + CSC * eh[k] * invh;
                float hi = -TAILV + 2.f * TAILV * cum;
                if (k == idx) { yk = lo; yk1 = hi; }
            }

            const float d0 = MINV + softplus_f(h2f(pp[2*NB + idx]));
            const float d1 = MINV + softplus_f(h2f(pp[2*NB + idx + 1]));

            const float wd = xk1 - xk, hd = yk1 - yk;
            const float sk = hd / wd;
            const float xi = (xc - xk) / wd;
            const float xim = xi * (1.f - xi);
            const float alpha = hd * (sk * xi * xi + d0 * xim);
            const float beta  = sk + (d1 + d0 - 2.f * sk) * xim;
            const float z     = yk + alpha / beta;
            const float om    = 1.f - xi;
            const float dn    = sk * sk * (d1 * xi * xi + 2.f * sk * xim + d0 * om * om);
            const float ld    = __logf(dn / (beta * beta));

            const bool inside = (x >= -TAILV) && (x <= TAILV);
            zout[(size_t)(row0 + r) * 32 + dim] = inside ? z : x;
            ldacc += inside ? ld : 0.f;
        }
    }
    sLDw[(lane & 31)*9 + wave*2 + (lane >> 5)] = ldacc;
    __syncthreads();

    // ---- phase 5: log_det reduction (8 partials per row) ----
    if (tid < 32) {
        float sld = 0.f;
        #pragma unroll
        for (int i = 0; i < 8; ++i) sld += sLDw[tid*9 + i];
        ldout[row0 + tid] = sld;
    }
}

extern "C" void kernel_launch(void* const* d_in, const int* in_sizes, int n_in,
                              void* d_out, int out_size, void* d_ws, size_t ws_size,
                              hipStream_t stream)
{
    const float* x1 = (const float*)d_in[0];
    const float* x2 = (const float*)d_in[1];
    const float* W1 = (const float*)d_in[2];
    const float* b1 = (const float*)d_in[3];
    const float* W2 = (const float*)d_in[4];
    const float* b2 = (const float*)d_in[5];
    const float* W3 = (const float*)d_in[6];
    const float* b3 = (const float*)d_in[7];

    // d_ws layout (1,204,224 B total)
    ushort* W3T = (ushort*)d_ws;                 // 2048*256 fp16 = 1 MB
    ushort* W2T = W3T + 2048 * 256;              // 256*256 fp16
    ushort* W1T = W2T + 256 * 256;               // 256*32 fp16
    float*  b3p = (float*)(W1T + 256 * 32);      // 2048 f32

    float* zout  = (float*)d_out;                // (65536, 32)
    float* ldout = zout + (size_t)65536 * 32;    // (65536,)

    cvt_weights<<<876, 256, 0, stream>>>(W1, W2, W3, b3, W3T, W2T, W1T, b3p);
    rq_mfma<<<2048, 256, 0, stream>>>(x1, x2, b1, b2, W1T, W2T, W3T, b3p, zout, ldout);
}

// Round 7
// 235.133 us; speedup vs baseline: 1.4614x; 1.4614x over previous
//
#include <hip/hip_runtime.h>
#include <cmath>

#define NB 16
#define TAILV 3.0f
#define MINV 0.001f
#define CSC 0.984f   // 1 - NB*MINV

typedef __attribute__((ext_vector_type(8))) _Float16 half8;
typedef __attribute__((ext_vector_type(4))) float f32x4;

#define MFMA16(a,b,c) __builtin_amdgcn_mfma_f32_16x16x32_f16(a,b,c,0,0,0)

__device__ __forceinline__ ushort f2h(float f) {
    union { _Float16 h; ushort u; } v; v.h = (_Float16)f; return v.u;
}
__device__ __forceinline__ float h2f(ushort u) {
    union { ushort u; _Float16 h; } v; v.u = u; return (float)v.h;
}
__device__ __forceinline__ float softplus_f(float x) {
    return (x > 20.0f) ? x : __logf(1.0f + __expf(x));   // fast-math: margin absorbs ~ulp error
}

// ---- prologue: convert/transpose weights into d_ws (fp16, [N][K]) ----
// W3T: [2048][256], n = dim*64 + p (p<49 real, else 0).  W2T: [256][256].  W1T: [256][32].
__global__ void __launch_bounds__(256)
cvt_weights(const float* __restrict__ W1, const float* __restrict__ W2,
            const float* __restrict__ W3, const float* __restrict__ b3,
            ushort* __restrict__ W3T, ushort* __restrict__ W2T,
            ushort* __restrict__ W1T, float* __restrict__ b3p)
{
    __shared__ float sm[64][65];
    const int b = blockIdx.x, t = threadIdx.x;
    const int tx = t & 63, ty = t >> 6;

    if (b < 100) {
        const int kt = b / 25, ct = b % 25;
        const int c = ct * 64 + tx;
        #pragma unroll
        for (int i = 0; i < 16; ++i) {
            const int k = kt * 64 + ty * 16 + i;
            float v = (c < 1568) ? W3[(size_t)k * 1568 + c] : 0.0f;
            sm[tx][ty * 16 + i] = v;               // sm[c_local][k_local]
        }
        __syncthreads();
        #pragma unroll
        for (int i = 0; i < 16; ++i) {
            const int clocal = ty * 16 + i;
            const int cc = ct * 64 + clocal;
            if (cc < 1568) {
                const int dim = cc / 49;
                const int p   = cc - dim * 49;
                const int n   = dim * 64 + p;
                W3T[(size_t)n * 256 + kt * 64 + tx] = f2h(sm[clocal][tx]);
            }
        }
    } else if (b < 580) {        // zero pad rows: n = dim*64 + 49 + q
        const int z = b - 100;
        const int dim = z / 15, q = z - dim * 15;
        const int n = dim * 64 + 49 + q;
        W3T[(size_t)n * 256 + t] = 0;
    } else if (b < 588) {        // b3p
        const int n = (b - 580) * 256 + t;
        const int dim = n >> 6, p = n & 63;
        b3p[n] = (p < 49) ? b3[dim * 49 + p] : 0.0f;
    } else if (b < 844) {        // W2T
        const int n = b - 588;
        W2T[(size_t)n * 256 + t] = f2h(W2[(size_t)t * 256 + n]);
    } else {                     // W1T (32 blocks, 8192 elems)
        const int idx = (b - 844) * 256 + t;
        const int n = idx >> 5, k = idx & 31;
        W1T[idx] = f2h(W1[(size_t)k * 256 + n]);
    }
}

// ---- fused main kernel: 64 batch rows / block, 4 waves, 1024 blocks ----
// WAVE-SPECIALIZED phase 4: waves 0-1 are pure GEMM producers (MFMA pipe),
// waves 2-3 are pure spline consumers (VALU/TRANS pipes). P is fp16,
// double-buffered (2 bufs x 2 gwaves x [64][50]); 17 barrier-locked steps:
// G writes P[t&1] while S consumes P[(t-1)&1]. Rationale (r6 post-mortem):
// per-wave GEMM<->spline alternation idles each pipe ~50%; m114 shows
// MFMA+VALU overlap fully ACROSS waves on a CU. Iso-occupancy (2 blocks/CU).
extern "C" __global__ void __launch_bounds__(256, 2)
rq_mfma(const float* __restrict__ x1, const float* __restrict__ x2,
        const float* __restrict__ b1, const float* __restrict__ b2,
        const ushort* __restrict__ W1T, const ushort* __restrict__ W2T,
        const ushort* __restrict__ W3T, const float* __restrict__ b3p,
        float* __restrict__ zout, float* __restrict__ ldout)
{
    __shared__ char smem[60416];
    float*  sX2  = (float*)smem;                    // [64][33] f32 = 8448
    float*  sLDw = (float*)(smem + 8448);           // [64][2] f32 (1280 reserved)
    char*   U    = smem + 9728;                     // 50688-byte union
    ushort* R0   = (ushort*)U;                      // [32][264] fp16 = 16896
    ushort* R1   = (ushort*)(U + 16896);            // [32][264]
    ushort* R2   = (ushort*)(U + 33792);            // [32][264]
    ushort* sA1  = R2;                              // [64][40] fp16 = 5120
    ushort* sP   = (ushort*)U;                      // 2buf x 2gw x [64][50] fp16 = 25600 overlay

    const int tid  = threadIdx.x;
    const int row0 = blockIdx.x * 64;
    const int rot  = blockIdx.x & 15;
    const int wave = tid >> 6, lane = tid & 63;
    const int ln = lane & 15, kg = lane >> 4;       // frag: m/n=ln, k-group=kg

    // ---- phase 0: stage x1 (->fp16, R2) and x2 (f32) ----
    {
        int r = tid >> 2, c = (tid & 3) << 3;
        float4 v0 = *(const float4*)(x1 + (size_t)(row0 + r) * 32 + c);
        float4 v1 = *(const float4*)(x1 + (size_t)(row0 + r) * 32 + c + 4);
        sA1[r*40 + c    ] = f2h(v0.x); sA1[r*40 + c + 1] = f2h(v0.y);
        sA1[r*40 + c + 2] = f2h(v0.z); sA1[r*40 + c + 3] = f2h(v0.w);
        sA1[r*40 + c + 4] = f2h(v1.x); sA1[r*40 + c + 5] = f2h(v1.y);
        sA1[r*40 + c + 6] = f2h(v1.z); sA1[r*40 + c + 7] = f2h(v1.w);
        float4 w0 = *(const float4*)(x2 + (size_t)(row0 + r) * 32 + c);
        float4 w1 = *(const float4*)(x2 + (size_t)(row0 + r) * 32 + c + 4);
        sX2[r*33 + c    ] = w0.x; sX2[r*33 + c + 1] = w0.y;
        sX2[r*33 + c + 2] = w0.z; sX2[r*33 + c + 3] = w0.w;
        sX2[r*33 + c + 4] = w1.x; sX2[r*33 + c + 5] = w1.y;
        sX2[r*33 + c + 6] = w1.z; sX2[r*33 + c + 7] = w1.w;
    }
    __syncthreads();

    // ---- phase 1: h1 = relu(x1 @ W1 + b1); 4 M-tiles, K=32 ----
    {
        half8 a[4];
        #pragma unroll
        for (int m = 0; m < 4; ++m)
            a[m] = *(const half8*)(sA1 + (m*16 + ln)*40 + kg*8);
        #pragma unroll
        for (int nt = 0; nt < 4; ++nt) {
            int n = wave*64 + nt*16 + ln;
            half8 bfr = *(const half8*)(W1T + n*32 + kg*8);
            float bias = b1[n];
            f32x4 zr = {0.f,0.f,0.f,0.f};
            #pragma unroll
            for (int m = 0; m < 4; ++m) {
                f32x4 cm = MFMA16(a[m], bfr, zr);
                ushort* dst = (m < 2) ? R0 : R1;
                int rb = (m & 1) * 16;
                #pragma unroll
                for (int g = 0; g < 4; ++g)
                    dst[(rb + kg*4 + g)*264 + n] = f2h(fmaxf(cm[g] + bias, 0.f));
            }
        }
    }
    __syncthreads();

    // ---- phase 2: h2 = relu(h1 @ W2 + b2), two 32-row half-passes ----
    #pragma unroll
    for (int part = 0; part < 2; ++part) {
        const ushort* S = (part == 0) ? R0 : R1;   // h1 rows
        ushort*       D = (part == 0) ? R2 : R0;   // h2 rows
        half8 a0[8], a1[8];
        #pragma unroll
        for (int ks = 0; ks < 8; ++ks) {
            a0[ks] = *(const half8*)(S + ln*264 + ks*32 + kg*8);
            a1[ks] = *(const half8*)(S + (16 + ln)*264 + ks*32 + kg*8);
        }
        #pragma unroll
        for (int nt = 0; nt < 4; ++nt) {
            int n = wave*64 + nt*16 + ln;
            f32x4 c0 = {0,0,0,0}, c1 = {0,0,0,0};
            const ushort* bp = W2T + (size_t)n*256 + kg*8;
            #pragma unroll
            for (int ks = 0; ks < 8; ++ks) {
                half8 bfr = *(const half8*)(bp + ks*32);
                c0 = MFMA16(a0[ks], bfr, c0);
                c1 = MFMA16(a1[ks], bfr, c1);
            }
            float bias = b2[n];
            #pragma unroll
            for (int g = 0; g < 4; ++g) {
                D[(kg*4 + g)*264 + n]      = f2h(fmaxf(c0[g] + bias, 0.f));
                D[(16 + kg*4 + g)*264 + n] = f2h(fmaxf(c1[g] + bias, 0.f));
            }
        }
        __syncthreads();
    }

    // ---- phase 3: GEMM waves hoist A-fragments (4 M-tiles x 8 ks) ----
    half8 A[4][8];
    half8 bcur[8], bnxt[8];
    if (wave < 2) {
        #pragma unroll
        for (int m = 0; m < 4; ++m) {
            const ushort* src = (m < 2) ? R2 : R0;  // h2 rows 0-31 / 32-63
            int rb = (m & 1) * 16;
            #pragma unroll
            for (int ks = 0; ks < 8; ++ks)
                A[m][ks] = *(const half8*)(src + (rb + ln)*264 + ks*32 + kg*8);
        }
    }
    __syncthreads();   // staging dead; sP overlays U

    // ---- phase 4: producer/consumer over 17 barrier-locked steps ----
    float ldacc = 0.f;
    if (wave < 2) {
        const int dim0 = wave*16 + rot;             // (t=0, nt=0) tile
        const ushort* bp = W3T + (size_t)(dim0*64 + ln)*256 + kg*8;
        #pragma unroll
        for (int ks = 0; ks < 8; ++ks) bcur[ks] = *(const half8*)(bp + ks*32);
    }

    for (int t = 0; t < 17; ++t) {
        if (wave < 2) {
            if (t < 16) {   // produce dim into P[t&1][wave]
                const int dim = wave*16 + ((t + rot) & 15);
                ushort* P = sP + ((t & 1)*2 + wave)*3200;
                float bias[4];
                #pragma unroll
                for (int nt = 0; nt < 4; ++nt) bias[nt] = b3p[dim*64 + nt*16 + ln];

                #pragma unroll
                for (int nt = 0; nt < 4; ++nt) {
                    const bool last = (t == 15) && (nt == 3);
                    if (!last) {   // prefetch next tile
                        int ndim = (nt == 3) ? (wave*16 + ((t + 1 + rot) & 15)) : dim;
                        int nnt  = (nt == 3) ? 0 : nt + 1;
                        const ushort* bp = W3T + (size_t)(ndim*64 + nnt*16 + ln)*256 + kg*8;
                        #pragma unroll
                        for (int ks = 0; ks < 8; ++ks) bnxt[ks] = *(const half8*)(bp + ks*32);
                    }
                    f32x4 c[4];
                    #pragma unroll
                    for (int m = 0; m < 4; ++m) c[m] = (f32x4){0,0,0,0};
                    #pragma unroll
                    for (int ks = 0; ks < 8; ++ks)
                        #pragma unroll
                        for (int m = 0; m < 4; ++m)
                            c[m] = MFMA16(A[m][ks], bcur[ks], c[m]);
                    int p = nt*16 + ln;
                    if (p < 49) {
                        #pragma unroll
                        for (int m = 0; m < 4; ++m)
                            #pragma unroll
                            for (int g = 0; g < 4; ++g)
                                P[(m*16 + kg*4 + g)*50 + p] = f2h(c[m][g] + bias[nt]);
                    }
                    if (!last) {
                        #pragma unroll
                        for (int ks = 0; ks < 8; ++ks) bcur[ks] = bnxt[ks];
                    }
                }
            }
        } else {
            if (t >= 1) {   // consume P[(t-1)&1][wave-2]; lane = row
                const int j   = wave - 2;
                const int dim = j*16 + ((t - 1 + rot) & 15);
                const ushort* pp = sP + (((t - 1) & 1)*2 + j)*3200 + lane*50;
                const float x  = sX2[lane*33 + dim];
                const float xc = fminf(fmaxf(x, -TAILV), TAILV);

                float e[NB]; float s = 0.f;
                #pragma unroll
                for (int k = 0; k < NB; ++k) { e[k] = __expf(h2f(pp[k])); s += e[k]; }
                const float inv = 1.f / s;

                int idx = 0; float xk = -TAILV, xk1 = TAILV; float cum = 0.f;
                #pragma unroll
                for (int k = 0; k < NB; ++k) {
                    float lo = -TAILV + 2.f * TAILV * cum;
                    cum += MINV + CSC * e[k] * inv;
                    float hi = -TAILV + 2.f * TAILV * cum;
                    if (lo <= xc) { idx = k; xk = lo; xk1 = hi; }
                }

                float eh[NB]; float sh = 0.f;
                #pragma unroll
                for (int k = 0; k < NB; ++k) { eh[k] = __expf(h2f(pp[NB + k])); sh += eh[k]; }
                const float invh = 1.f / sh;

                float yk = -TAILV, yk1 = TAILV; cum = 0.f;
                #pragma unroll
                for (int k = 0; k < NB; ++k) {
                    float lo = -TAILV + 2.f * TAILV * cum;
                    cum += MINV + CSC * eh[k] * invh;
                    float hi = -TAILV + 2.f * TAILV * cum;
                    if (k == idx) { yk = lo; yk1 = hi; }
                }

                const float d0 = MINV + softplus_f(h2f(pp[2*NB + idx]));
                const float d1 = MINV + softplus_f(h2f(pp[2*NB + idx + 1]));

                const float wd = xk1 - xk, hd = yk1 - yk;
                const float sk = hd / wd;
                const float xi = (xc - xk) / wd;
                const float xim = xi * (1.f - xi);
                const float alpha = hd * (sk * xi * xi + d0 * xim);
                const float beta  = sk + (d1 + d0 - 2.f * sk) * xim;
                const float z     = yk + alpha / beta;
                const float om    = 1.f - xi;
                const float dn    = sk * sk * (d1 * xi * xi + 2.f * sk * xim + d0 * om * om);
                const float ld    = __logf(dn / (beta * beta));

                const bool inside = (x >= -TAILV) && (x <= TAILV);
                zout[(size_t)(row0 + lane) * 32 + dim] = inside ? z : x;
                ldacc += inside ? ld : 0.f;
            }
        }
        __syncthreads();
    }

    // ---- phase 5: log_det reduction (2 spline partials per row) ----
    if (wave >= 2) sLDw[lane*2 + (wave - 2)] = ldacc;
    __syncthreads();
    if (tid < 64) ldout[row0 + tid] = sLDw[tid*2] + sLDw[tid*2 + 1];
}

extern "C" void kernel_launch(void* const* d_in, const int* in_sizes, int n_in,
                              void* d_out, int out_size, void* d_ws, size_t ws_size,
                              hipStream_t stream)
{
    const float* x1 = (const float*)d_in[0];
    const float* x2 = (const float*)d_in[1];
    const float* W1 = (const float*)d_in[2];
    const float* b1 = (const float*)d_in[3];
    const float* W2 = (const float*)d_in[4];
    const float* b2 = (const float*)d_in[5];
    const float* W3 = (const float*)d_in[6];
    const float* b3 = (const float*)d_in[7];

    // d_ws layout (1,204,224 B total)
    ushort* W3T = (ushort*)d_ws;                 // 2048*256 fp16 = 1 MB
    ushort* W2T = W3T + 2048 * 256;              // 256*256 fp16
    ushort* W1T = W2T + 256 * 256;               // 256*32 fp16
    float*  b3p = (float*)(W1T + 256 * 32);      // 2048 f32

    float* zout  = (float*)d_out;                // (65536, 32)
    float* ldout = zout + (size_t)65536 * 32;    // (65536,)

    cvt_weights<<<876, 256, 0, stream>>>(W1, W2, W3, b3, W3T, W2T, W1T, b3p);
    rq_mfma<<<1024, 256, 0, stream>>>(x1, x2, b1, b2, W1T, W2T, W3T, b3p, zout, ldout);
}

// Round 9
// 234.076 us; speedup vs baseline: 1.4680x; 1.0045x over previous
//
#include <hip/hip_runtime.h>
#include <cmath>

#define NB 16
#define TAILV 3.0f
#define MINV 0.001f
#define CSC 0.984f   // 1 - NB*MINV

typedef __attribute__((ext_vector_type(8))) _Float16 half8;
typedef __attribute__((ext_vector_type(4))) float f32x4;

#define MFMA16(a,b,c) __builtin_amdgcn_mfma_f32_16x16x32_f16(a,b,c,0,0,0)

__device__ __forceinline__ ushort f2h(float f) {
    union { _Float16 h; ushort u; } v; v.h = (_Float16)f; return v.u;
}
__device__ __forceinline__ float softplus_f(float x) {
    return (x > 20.0f) ? x : __logf(1.0f + __expf(x));   // fast-math: margin absorbs ~ulp error
}

// ---- prologue: convert/transpose weights into d_ws (fp16, [N][K]) ----
// W3T: [2048][256], n = dim*64 + p (p<49 real, else 0).  W2T: [256][256].  W1T: [256][32].
__global__ void __launch_bounds__(256)
cvt_weights(const float* __restrict__ W1, const float* __restrict__ W2,
            const float* __restrict__ W3, const float* __restrict__ b3,
            ushort* __restrict__ W3T, ushort* __restrict__ W2T,
            ushort* __restrict__ W1T, float* __restrict__ b3p)
{
    __shared__ float sm[64][65];
    const int b = blockIdx.x, t = threadIdx.x;
    const int tx = t & 63, ty = t >> 6;

    if (b < 100) {
        const int kt = b / 25, ct = b % 25;
        const int c = ct * 64 + tx;
        #pragma unroll
        for (int i = 0; i < 16; ++i) {
            const int k = kt * 64 + ty * 16 + i;
            float v = (c < 1568) ? W3[(size_t)k * 1568 + c] : 0.0f;
            sm[tx][ty * 16 + i] = v;               // sm[c_local][k_local]
        }
        __syncthreads();
        #pragma unroll
        for (int i = 0; i < 16; ++i) {
            const int clocal = ty * 16 + i;
            const int cc = ct * 64 + clocal;
            if (cc < 1568) {
                const int dim = cc / 49;
                const int p   = cc - dim * 49;
                const int n   = dim * 64 + p;
                W3T[(size_t)n * 256 + kt * 64 + tx] = f2h(sm[clocal][tx]);
            }
        }
    } else if (b < 580) {        // zero pad rows: n = dim*64 + 49 + q
        const int z = b - 100;
        const int dim = z / 15, q = z - dim * 15;
        const int n = dim * 64 + 49 + q;
        W3T[(size_t)n * 256 + t] = 0;
    } else if (b < 588) {        // b3p
        const int n = (b - 580) * 256 + t;
        const int dim = n >> 6, p = n & 63;
        b3p[n] = (p < 49) ? b3[dim * 49 + p] : 0.0f;
    } else if (b < 844) {        // W2T
        const int n = b - 588;
        W2T[(size_t)n * 256 + t] = f2h(W2[(size_t)t * 256 + n]);
    } else {                     // W1T (32 blocks, 8192 elems)
        const int idx = (b - 844) * 256 + t;
        const int n = idx >> 5, k = idx & 31;
        W1T[idx] = f2h(W1[(size_t)k * 256 + n]);
    }
}

// ---- fused main kernel: 64 batch rows / block, 4 waves, 1024 blocks ----
// Phase 4 dataflow fix (r7 post-mortem: schedules neutral; the invariant
// across all neutral variants is the P LDS round-trip as ~113 scalar u16
// DS ops/chunk/wave + fp16 pack/unpack):
//   - P is f32, single-buffered [64][52] (16B-aligned rows)
//   - spline loads widths/heights via 8x ds_read_b128 (1 batched lgkm wait)
//   - only the 2 deriv gathers use computed-address scalar LDS reads
//     (runtime idx must not index a register array - scratch trap)
//   - zero f2h/h2f in phase 4
extern "C" __global__ void __launch_bounds__(256, 2)
rq_mfma(const float* __restrict__ x1, const float* __restrict__ x2,
        const float* __restrict__ b1, const float* __restrict__ b2,
        const ushort* __restrict__ W1T, const ushort* __restrict__ W2T,
        const ushort* __restrict__ W3T, const float* __restrict__ b3p,
        float* __restrict__ zout, float* __restrict__ ldout)
{
    __shared__ char smem[62976];
    float*  sX2  = (float*)smem;                    // [64][33] f32 = 8448
    float*  sLDw = (float*)(smem + 8448);           // [64][5] f32 = 1280
    char*   U    = smem + 9728;                     // 53248-byte union
    ushort* R0   = (ushort*)U;                      // [32][264] fp16 = 16896
    ushort* R1   = (ushort*)(U + 16896);            // [32][264]
    ushort* R2   = (ushort*)(U + 33792);            // [32][264]
    ushort* sA1  = R2;                              // [64][40] fp16 = 5120
    float*  sPw  = (float*)U;                       // 4 waves x [64][52] f32 = 53248

    const int tid  = threadIdx.x;
    const int row0 = blockIdx.x * 64;
    const int rot  = blockIdx.x & 7;
    const int wave = tid >> 6, lane = tid & 63;
    const int ln = lane & 15, kg = lane >> 4;       // frag: m/n=ln, k-group=kg

    // ---- phase 0: stage x1 (->fp16, R2) and x2 (f32) ----
    {
        int r = tid >> 2, c = (tid & 3) << 3;
        float4 v0 = *(const float4*)(x1 + (size_t)(row0 + r) * 32 + c);
        float4 v1 = *(const float4*)(x1 + (size_t)(row0 + r) * 32 + c + 4);
        sA1[r*40 + c    ] = f2h(v0.x); sA1[r*40 + c + 1] = f2h(v0.y);
        sA1[r*40 + c + 2] = f2h(v0.z); sA1[r*40 + c + 3] = f2h(v0.w);
        sA1[r*40 + c + 4] = f2h(v1.x); sA1[r*40 + c + 5] = f2h(v1.y);
        sA1[r*40 + c + 6] = f2h(v1.z); sA1[r*40 + c + 7] = f2h(v1.w);
        float4 w0 = *(const float4*)(x2 + (size_t)(row0 + r) * 32 + c);
        float4 w1 = *(const float4*)(x2 + (size_t)(row0 + r) * 32 + c + 4);
        sX2[r*33 + c    ] = w0.x; sX2[r*33 + c + 1] = w0.y;
        sX2[r*33 + c + 2] = w0.z; sX2[r*33 + c + 3] = w0.w;
        sX2[r*33 + c + 4] = w1.x; sX2[r*33 + c + 5] = w1.y;
        sX2[r*33 + c + 6] = w1.z; sX2[r*33 + c + 7] = w1.w;
    }
    __syncthreads();

    // ---- phase 1: h1 = relu(x1 @ W1 + b1); 4 M-tiles, K=32 ----
    {
        half8 a[4];
        #pragma unroll
        for (int m = 0; m < 4; ++m)
            a[m] = *(const half8*)(sA1 + (m*16 + ln)*40 + kg*8);
        #pragma unroll
        for (int nt = 0; nt < 4; ++nt) {
            int n = wave*64 + nt*16 + ln;
            half8 bfr = *(const half8*)(W1T + n*32 + kg*8);
            float bias = b1[n];
            f32x4 zr = {0.f,0.f,0.f,0.f};
            #pragma unroll
            for (int m = 0; m < 4; ++m) {
                f32x4 cm = MFMA16(a[m], bfr, zr);
                ushort* dst = (m < 2) ? R0 : R1;
                int rb = (m & 1) * 16;
                #pragma unroll
                for (int g = 0; g < 4; ++g)
                    dst[(rb + kg*4 + g)*264 + n] = f2h(fmaxf(cm[g] + bias, 0.f));
            }
        }
    }
    __syncthreads();

    // ---- phase 2: h2 = relu(h1 @ W2 + b2), two 32-row half-passes ----
    #pragma unroll
    for (int part = 0; part < 2; ++part) {
        const ushort* S = (part == 0) ? R0 : R1;   // h1 rows
        ushort*       D = (part == 0) ? R2 : R0;   // h2 rows
        half8 a0[8], a1[8];
        #pragma unroll
        for (int ks = 0; ks < 8; ++ks) {
            a0[ks] = *(const half8*)(S + ln*264 + ks*32 + kg*8);
            a1[ks] = *(const half8*)(S + (16 + ln)*264 + ks*32 + kg*8);
        }
        #pragma unroll
        for (int nt = 0; nt < 4; ++nt) {
            int n = wave*64 + nt*16 + ln;
            f32x4 c0 = {0,0,0,0}, c1 = {0,0,0,0};
            const ushort* bp = W2T + (size_t)n*256 + kg*8;
            #pragma unroll
            for (int ks = 0; ks < 8; ++ks) {
                half8 bfr = *(const half8*)(bp + ks*32);
                c0 = MFMA16(a0[ks], bfr, c0);
                c1 = MFMA16(a1[ks], bfr, c1);
            }
            float bias = b2[n];
            #pragma unroll
            for (int g = 0; g < 4; ++g) {
                D[(kg*4 + g)*264 + n]      = f2h(fmaxf(c0[g] + bias, 0.f));
                D[(16 + kg*4 + g)*264 + n] = f2h(fmaxf(c1[g] + bias, 0.f));
            }
        }
        __syncthreads();
    }

    // ---- phase 3: hoist GEMM3 A-fragments (4 M-tiles x 8 ks = 128 regs) ----
    half8 A[4][8];
    #pragma unroll
    for (int m = 0; m < 4; ++m) {
        const ushort* src = (m < 2) ? R2 : R0;     // h2 rows 0-31 / 32-63
        int rb = (m & 1) * 16;
        #pragma unroll
        for (int ks = 0; ks < 8; ++ks)
            A[m][ks] = *(const half8*)(src + (rb + ln)*264 + ks*32 + kg*8);
    }
    __syncthreads();   // staging dead; sPw overlays U

    // ---- phase 4: GEMM3 + fused spline; wave owns dims [wave*8, wave*8+8) ----
    float* myP = sPw + wave * (64 * 52);           // [64][52] f32
    float  ldacc = 0.f;

    half8 bcur[8], bnxt[8];
    {
        int dim0 = wave*8 + rot;
        const ushort* bp = W3T + (size_t)(dim0*64 + ln)*256 + kg*8;
        #pragma unroll
        for (int ks = 0; ks < 8; ++ks) bcur[ks] = *(const half8*)(bp + ks*32);
    }

    for (int ch0 = 0; ch0 < 8; ++ch0) {
        const int dim = wave*8 + ((ch0 + rot) & 7);
        float bias[4];
        #pragma unroll
        for (int nt = 0; nt < 4; ++nt) bias[nt] = b3p[dim*64 + nt*16 + ln];

        #pragma unroll
        for (int nt = 0; nt < 4; ++nt) {
            const bool last = (ch0 == 7) && (nt == 3);
            if (!last) {   // prefetch next tile (rotated order)
                int ndim = (nt == 3) ? (wave*8 + ((ch0 + 1 + rot) & 7)) : dim;
                int nnt  = (nt == 3) ? 0 : nt + 1;
                const ushort* bp = W3T + (size_t)(ndim*64 + nnt*16 + ln)*256 + kg*8;
                #pragma unroll
                for (int ks = 0; ks < 8; ++ks) bnxt[ks] = *(const half8*)(bp + ks*32);
            }
            f32x4 c[4];
            #pragma unroll
            for (int m = 0; m < 4; ++m) c[m] = (f32x4){0,0,0,0};
            #pragma unroll
            for (int ks = 0; ks < 8; ++ks)
                #pragma unroll
                for (int m = 0; m < 4; ++m)
                    c[m] = MFMA16(A[m][ks], bcur[ks], c[m]);
            int p = nt*16 + ln;
            if (p < 49) {
                #pragma unroll
                for (int m = 0; m < 4; ++m)
                    #pragma unroll
                    for (int g = 0; g < 4; ++g)
                        myP[(m*16 + kg*4 + g)*52 + p] = c[m][g] + bias[nt];
            }
            if (!last) {
                #pragma unroll
                for (int ks = 0; ks < 8; ++ks) bcur[ks] = bnxt[ks];
            }
        }

        // spline: 64 rows x 1 dim = 1 task/lane (r = lane). Widths/heights
        // via 8x b128 vector loads (static component indexing); derivs via
        // 2 computed-address scalar LDS reads. Math identical to r5-verified
        // body (no-max softmax, fused log), now in f32 end-to-end.
        {
            const float* myPl = myP + lane * 52;
            const f32x4* pr   = (const f32x4*)myPl;
            const float x  = sX2[lane*33 + dim];
            const float xc = fminf(fmaxf(x, -TAILV), TAILV);

            f32x4 Lw[4], Lh[4];
            #pragma unroll
            for (int q = 0; q < 4; ++q) Lw[q] = pr[q];       // p 0..15
            #pragma unroll
            for (int q = 0; q < 4; ++q) Lh[q] = pr[4 + q];   // p 16..31

            float e[NB]; float s = 0.f;
            #pragma unroll
            for (int k = 0; k < NB; ++k) { e[k] = __expf(Lw[k>>2][k&3]); s += e[k]; }
            const float inv = 1.f / s;

            int idx = 0; float xk = -TAILV, xk1 = TAILV; float cum = 0.f;
            #pragma unroll
            for (int k = 0; k < NB; ++k) {
                float lo = -TAILV + 2.f * TAILV * cum;
                cum += MINV + CSC * e[k] * inv;
                float hi = -TAILV + 2.f * TAILV * cum;
                if (lo <= xc) { idx = k; xk = lo; xk1 = hi; }
            }

            float eh[NB]; float sh = 0.f;
            #pragma unroll
            for (int k = 0; k < NB; ++k) { eh[k] = __expf(Lh[k>>2][k&3]); sh += eh[k]; }
            const float invh = 1.f / sh;

            float yk = -TAILV, yk1 = TAILV; cum = 0.f;
            #pragma unroll
            for (int k = 0; k < NB; ++k) {
                float lo = -TAILV + 2.f * TAILV * cum;
                cum += MINV + CSC * eh[k] * invh;
                float hi = -TAILV + 2.f * TAILV * cum;
                if (k == idx) { yk = lo; yk1 = hi; }
            }

            const float d0 = MINV + softplus_f(myPl[2*NB + idx]);
            const float d1 = MINV + softplus_f(myPl[2*NB + idx + 1]);

            const float wd = xk1 - xk, hd = yk1 - yk;
            const float sk = hd / wd;
            const float xi = (xc - xk) / wd;
            const float xim = xi * (1.f - xi);
            const float alpha = hd * (sk * xi * xi + d0 * xim);
            const float beta  = sk + (d1 + d0 - 2.f * sk) * xim;
            const float z     = yk + alpha / beta;
            const float om    = 1.f - xi;
            const float dn    = sk * sk * (d1 * xi * xi + 2.f * sk * xim + d0 * om * om);
            const float ld    = __logf(dn / (beta * beta));

            const bool inside = (x >= -TAILV) && (x <= TAILV);
            zout[(size_t)(row0 + lane) * 32 + dim] = inside ? z : x;
            ldacc += inside ? ld : 0.f;
        }
    }
    sLDw[lane*5 + wave] = ldacc;
    __syncthreads();

    // ---- phase 5: log_det reduction across waves ----
    if (tid < 64) {
        float sld = sLDw[tid*5 + 0] + sLDw[tid*5 + 1]
                  + sLDw[tid*5 + 2] + sLDw[tid*5 + 3];
        ldout[row0 + tid] = sld;
    }
}

extern "C" void kernel_launch(void* const* d_in, const int* in_sizes, int n_in,
                              void* d_out, int out_size, void* d_ws, size_t ws_size,
                              hipStream_t stream)
{
    const float* x1 = (const float*)d_in[0];
    const float* x2 = (const float*)d_in[1];
    const float* W1 = (const float*)d_in[2];
    const float* b1 = (const float*)d_in[3];
    const float* W2 = (const float*)d_in[4];
    const float* b2 = (const float*)d_in[5];
    const float* W3 = (const float*)d_in[6];
    const float* b3 = (const float*)d_in[7];

    // d_ws layout (1,204,224 B total)
    ushort* W3T = (ushort*)d_ws;                 // 2048*256 fp16 = 1 MB
    ushort* W2T = W3T + 2048 * 256;              // 256*256 fp16
    ushort* W1T = W2T + 256 * 256;               // 256*32 fp16
    float*  b3p = (float*)(W1T + 256 * 32);      // 2048 f32

    float* zout  = (float*)d_out;                // (65536, 32)
    float* ldout = zout + (size_t)65536 * 32;    // (65536,)

    cvt_weights<<<876, 256, 0, stream>>>(W1, W2, W3, b3, W3T, W2T, W1T, b3p);
    rq_mfma<<<1024, 256, 0, stream>>>(x1, x2, b1, b2, W1T, W2T, W3T, b3p, zout, ldout);
}

// Round 12
// 232.830 us; speedup vs baseline: 1.4759x; 1.0054x over previous
//
#include <hip/hip_runtime.h>
#include <cmath>

#define NB 16
#define TAILV 3.0f
#define MINV 0.001f
#define CSC 0.984f   // 1 - NB*MINV

typedef __attribute__((ext_vector_type(8))) _Float16 half8;
typedef __attribute__((ext_vector_type(4))) float f32x4;

#define MFMA16(a,b,c) __builtin_amdgcn_mfma_f32_16x16x32_f16(a,b,c,0,0,0)

__device__ __forceinline__ ushort f2h(float f) {
    union { _Float16 h; ushort u; } v; v.h = (_Float16)f; return v.u;
}
__device__ __forceinline__ float softplus_f(float x) {
    return (x > 20.0f) ? x : __logf(1.0f + __expf(x));   // fast-math: margin absorbs ~ulp error
}

// ---- prologue: convert/transpose weights into d_ws (fp16, [N][K]) ----
// W3T: [2048][256], n = dim*64 + p (p<49 real, else 0).  W2T: [256][256].  W1T: [256][32].
__global__ void __launch_bounds__(256)
cvt_weights(const float* __restrict__ W1, const float* __restrict__ W2,
            const float* __restrict__ W3, const float* __restrict__ b3,
            ushort* __restrict__ W3T, ushort* __restrict__ W2T,
            ushort* __restrict__ W1T, float* __restrict__ b3p)
{
    __shared__ float sm[64][65];
    const int b = blockIdx.x, t = threadIdx.x;
    const int tx = t & 63, ty = t >> 6;

    if (b < 100) {
        const int kt = b / 25, ct = b % 25;
        const int c = ct * 64 + tx;
        #pragma unroll
        for (int i = 0; i < 16; ++i) {
            const int k = kt * 64 + ty * 16 + i;
            float v = (c < 1568) ? W3[(size_t)k * 1568 + c] : 0.0f;
            sm[tx][ty * 16 + i] = v;               // sm[c_local][k_local]
        }
        __syncthreads();
        #pragma unroll
        for (int i = 0; i < 16; ++i) {
            const int clocal = ty * 16 + i;
            const int cc = ct * 64 + clocal;
            if (cc < 1568) {
                const int dim = cc / 49;
                const int p   = cc - dim * 49;
                const int n   = dim * 64 + p;
                W3T[(size_t)n * 256 + kt * 64 + tx] = f2h(sm[clocal][tx]);
            }
        }
    } else if (b < 580) {        // zero pad rows: n = dim*64 + 49 + q
        const int z = b - 100;
        const int dim = z / 15, q = z - dim * 15;
        const int n = dim * 64 + 49 + q;
        W3T[(size_t)n * 256 + t] = 0;
    } else if (b < 588) {        // b3p
        const int n = (b - 580) * 256 + t;
        const int dim = n >> 6, p = n & 63;
        b3p[n] = (p < 49) ? b3[dim * 49 + p] : 0.0f;
    } else if (b < 844) {        // W2T
        const int n = b - 588;
        W2T[(size_t)n * 256 + t] = f2h(W2[(size_t)t * 256 + n]);
    } else {                     // W1T (32 blocks, 8192 elems)
        const int idx = (b - 844) * 256 + t;
        const int n = idx >> 5, k = idx & 31;
        W1T[idx] = f2h(W1[(size_t)k * 256 + n]);
    }
}

// ---- fused main kernel: 64 batch rows / block, 4 waves, 1024 blocks ----
// r12 = r9 (last verified, 173.5us) + ONE change: softmax denominator sums
// are depth-4 tree sums instead of 16-deep serial chains (pure fp
// reassociation). Everything else byte-identical to r9. The r10/r11
// select-tree gather arc is abandoned (two unexplained codegen-level
// failures); serial latch scans below are the r9-verified originals.
extern "C" __global__ void __launch_bounds__(256, 2)
rq_mfma(const float* __restrict__ x1, const float* __restrict__ x2,
        const float* __restrict__ b1, const float* __restrict__ b2,
        const ushort* __restrict__ W1T, const ushort* __restrict__ W2T,
        const ushort* __restrict__ W3T, const float* __restrict__ b3p,
        float* __restrict__ zout, float* __restrict__ ldout)
{
    __shared__ char smem[62976];
    float*  sX2  = (float*)smem;                    // [64][33] f32 = 8448
    float*  sLDw = (float*)(smem + 8448);           // [64][5] f32 = 1280
    char*   U    = smem + 9728;                     // 53248-byte union
    ushort* R0   = (ushort*)U;                      // [32][264] fp16 = 16896
    ushort* R1   = (ushort*)(U + 16896);            // [32][264]
    ushort* R2   = (ushort*)(U + 33792);            // [32][264]
    ushort* sA1  = R2;                              // [64][40] fp16 = 5120
    float*  sPw  = (float*)U;                       // 4 waves x [64][52] f32 = 53248

    const int tid  = threadIdx.x;
    const int row0 = blockIdx.x * 64;
    const int rot  = blockIdx.x & 7;
    const int wave = tid >> 6, lane = tid & 63;
    const int ln = lane & 15, kg = lane >> 4;       // frag: m/n=ln, k-group=kg

    // ---- phase 0: stage x1 (->fp16, R2) and x2 (f32) ----
    {
        int r = tid >> 2, c = (tid & 3) << 3;
        float4 v0 = *(const float4*)(x1 + (size_t)(row0 + r) * 32 + c);
        float4 v1 = *(const float4*)(x1 + (size_t)(row0 + r) * 32 + c + 4);
        sA1[r*40 + c    ] = f2h(v0.x); sA1[r*40 + c + 1] = f2h(v0.y);
        sA1[r*40 + c + 2] = f2h(v0.z); sA1[r*40 + c + 3] = f2h(v0.w);
        sA1[r*40 + c + 4] = f2h(v1.x); sA1[r*40 + c + 5] = f2h(v1.y);
        sA1[r*40 + c + 6] = f2h(v1.z); sA1[r*40 + c + 7] = f2h(v1.w);
        float4 w0 = *(const float4*)(x2 + (size_t)(row0 + r) * 32 + c);
        float4 w1 = *(const float4*)(x2 + (size_t)(row0 + r) * 32 + c + 4);
        sX2[r*33 + c    ] = w0.x; sX2[r*33 + c + 1] = w0.y;
        sX2[r*33 + c + 2] = w0.z; sX2[r*33 + c + 3] = w0.w;
        sX2[r*33 + c + 4] = w1.x; sX2[r*33 + c + 5] = w1.y;
        sX2[r*33 + c + 6] = w1.z; sX2[r*33 + c + 7] = w1.w;
    }
    __syncthreads();

    // ---- phase 1: h1 = relu(x1 @ W1 + b1); 4 M-tiles, K=32 ----
    {
        half8 a[4];
        #pragma unroll
        for (int m = 0; m < 4; ++m)
            a[m] = *(const half8*)(sA1 + (m*16 + ln)*40 + kg*8);
        #pragma unroll
        for (int nt = 0; nt < 4; ++nt) {
            int n = wave*64 + nt*16 + ln;
            half8 bfr = *(const half8*)(W1T + n*32 + kg*8);
            float bias = b1[n];
            f32x4 zr = {0.f,0.f,0.f,0.f};
            #pragma unroll
            for (int m = 0; m < 4; ++m) {
                f32x4 cm = MFMA16(a[m], bfr, zr);
                ushort* dst = (m < 2) ? R0 : R1;
                int rb = (m & 1) * 16;
                #pragma unroll
                for (int g = 0; g < 4; ++g)
                    dst[(rb + kg*4 + g)*264 + n] = f2h(fmaxf(cm[g] + bias, 0.f));
            }
        }
    }
    __syncthreads();

    // ---- phase 2: h2 = relu(h1 @ W2 + b2), two 32-row half-passes ----
    #pragma unroll
    for (int part = 0; part < 2; ++part) {
        const ushort* S = (part == 0) ? R0 : R1;   // h1 rows
        ushort*       D = (part == 0) ? R2 : R0;   // h2 rows
        half8 a0[8], a1[8];
        #pragma unroll
        for (int ks = 0; ks < 8; ++ks) {
            a0[ks] = *(const half8*)(S + ln*264 + ks*32 + kg*8);
            a1[ks] = *(const half8*)(S + (16 + ln)*264 + ks*32 + kg*8);
        }
        #pragma unroll
        for (int nt = 0; nt < 4; ++nt) {
            int n = wave*64 + nt*16 + ln;
            f32x4 c0 = {0,0,0,0}, c1 = {0,0,0,0};
            const ushort* bp = W2T + (size_t)n*256 + kg*8;
            #pragma unroll
            for (int ks = 0; ks < 8; ++ks) {
                half8 bfr = *(const half8*)(bp + ks*32);
                c0 = MFMA16(a0[ks], bfr, c0);
                c1 = MFMA16(a1[ks], bfr, c1);
            }
            float bias = b2[n];
            #pragma unroll
            for (int g = 0; g < 4; ++g) {
                D[(kg*4 + g)*264 + n]      = f2h(fmaxf(c0[g] + bias, 0.f));
                D[(16 + kg*4 + g)*264 + n] = f2h(fmaxf(c1[g] + bias, 0.f));
            }
        }
        __syncthreads();
    }

    // ---- phase 3: hoist GEMM3 A-fragments (4 M-tiles x 8 ks = 128 regs) ----
    half8 A[4][8];
    #pragma unroll
    for (int m = 0; m < 4; ++m) {
        const ushort* src = (m < 2) ? R2 : R0;     // h2 rows 0-31 / 32-63
        int rb = (m & 1) * 16;
        #pragma unroll
        for (int ks = 0; ks < 8; ++ks)
            A[m][ks] = *(const half8*)(src + (rb + ln)*264 + ks*32 + kg*8);
    }
    __syncthreads();   // staging dead; sPw overlays U

    // ---- phase 4: GEMM3 + fused spline; wave owns dims [wave*8, wave*8+8) ----
    float* myP = sPw + wave * (64 * 52);           // [64][52] f32
    float  ldacc = 0.f;

    half8 bcur[8], bnxt[8];
    {
        int dim0 = wave*8 + rot;
        const ushort* bp = W3T + (size_t)(dim0*64 + ln)*256 + kg*8;
        #pragma unroll
        for (int ks = 0; ks < 8; ++ks) bcur[ks] = *(const half8*)(bp + ks*32);
    }

    for (int ch0 = 0; ch0 < 8; ++ch0) {
        const int dim = wave*8 + ((ch0 + rot) & 7);
        float bias[4];
        #pragma unroll
        for (int nt = 0; nt < 4; ++nt) bias[nt] = b3p[dim*64 + nt*16 + ln];

        #pragma unroll
        for (int nt = 0; nt < 4; ++nt) {
            const bool last = (ch0 == 7) && (nt == 3);
            if (!last) {   // prefetch next tile (rotated order)
                int ndim = (nt == 3) ? (wave*8 + ((ch0 + 1 + rot) & 7)) : dim;
                int nnt  = (nt == 3) ? 0 : nt + 1;
                const ushort* bp = W3T + (size_t)(ndim*64 + nnt*16 + ln)*256 + kg*8;
                #pragma unroll
                for (int ks = 0; ks < 8; ++ks) bnxt[ks] = *(const half8*)(bp + ks*32);
            }
            f32x4 c[4];
            #pragma unroll
            for (int m = 0; m < 4; ++m) c[m] = (f32x4){0,0,0,0};
            #pragma unroll
            for (int ks = 0; ks < 8; ++ks)
                #pragma unroll
                for (int m = 0; m < 4; ++m)
                    c[m] = MFMA16(A[m][ks], bcur[ks], c[m]);
            int p = nt*16 + ln;
            if (p < 49) {
                #pragma unroll
                for (int m = 0; m < 4; ++m)
                    #pragma unroll
                    for (int g = 0; g < 4; ++g)
                        myP[(m*16 + kg*4 + g)*52 + p] = c[m][g] + bias[nt];
            }
            if (!last) {
                #pragma unroll
                for (int ks = 0; ks < 8; ++ks) bcur[ks] = bnxt[ks];
            }
        }

        // spline: 64 rows x 1 dim = 1 task/lane (r = lane). Identical to the
        // r9-verified body except the two denominator sums are depth-4 trees.
        {
            const float* myPl = myP + lane * 52;
            const f32x4* pr   = (const f32x4*)myPl;
            const float x  = sX2[lane*33 + dim];
            const float xc = fminf(fmaxf(x, -TAILV), TAILV);

            f32x4 Lw[4], Lh[4];
            #pragma unroll
            for (int q = 0; q < 4; ++q) Lw[q] = pr[q];       // p 0..15
            #pragma unroll
            for (int q = 0; q < 4; ++q) Lh[q] = pr[4 + q];   // p 16..31

            float e[NB];
            #pragma unroll
            for (int k = 0; k < NB; ++k) e[k] = __expf(Lw[k>>2][k&3]);
            float s;
            {
                float a0=e[0]+e[1],   a1=e[2]+e[3],   a2=e[4]+e[5],   a3=e[6]+e[7];
                float a4=e[8]+e[9],   a5=e[10]+e[11], a6=e[12]+e[13], a7=e[14]+e[15];
                s = ((a0+a1)+(a2+a3)) + ((a4+a5)+(a6+a7));
            }
            const float inv = 1.f / s;

            int idx = 0; float xk = -TAILV, xk1 = TAILV; float cum = 0.f;
            #pragma unroll
            for (int k = 0; k < NB; ++k) {
                float lo = -TAILV + 2.f * TAILV * cum;
                cum += MINV + CSC * e[k] * inv;
                float hi = -TAILV + 2.f * TAILV * cum;
                if (lo <= xc) { idx = k; xk = lo; xk1 = hi; }
            }

            float eh[NB];
            #pragma unroll
            for (int k = 0; k < NB; ++k) eh[k] = __expf(Lh[k>>2][k&3]);
            float sh;
            {
                float a0=eh[0]+eh[1],   a1=eh[2]+eh[3],   a2=eh[4]+eh[5],   a3=eh[6]+eh[7];
                float a4=eh[8]+eh[9],   a5=eh[10]+eh[11], a6=eh[12]+eh[13], a7=eh[14]+eh[15];
                sh = ((a0+a1)+(a2+a3)) + ((a4+a5)+(a6+a7));
            }
            const float invh = 1.f / sh;

            float yk = -TAILV, yk1 = TAILV; cum = 0.f;
            #pragma unroll
            for (int k = 0; k < NB; ++k) {
                float lo = -TAILV + 2.f * TAILV * cum;
                cum += MINV + CSC * eh[k] * invh;
                float hi = -TAILV + 2.f * TAILV * cum;
                if (k == idx) { yk = lo; yk1 = hi; }
            }

            const float d0 = MINV + softplus_f(myPl[2*NB + idx]);
            const float d1 = MINV + softplus_f(myPl[2*NB + idx + 1]);

            const float wd = xk1 - xk, hd = yk1 - yk;
            const float sk = hd / wd;
            const float xi = (xc - xk) / wd;
            const float xim = xi * (1.f - xi);
            const float alpha = hd * (sk * xi * xi + d0 * xim);
            const float beta  = sk + (d1 + d0 - 2.f * sk) * xim;
            const float z     = yk + alpha / beta;
            const float om    = 1.f - xi;
            const float dn    = sk * sk * (d1 * xi * xi + 2.f * sk * xim + d0 * om * om);
            const float ld    = __logf(dn / (beta * beta));

            const bool inside = (x >= -TAILV) && (x <= TAILV);
            zout[(size_t)(row0 + lane) * 32 + dim] = inside ? z : x;
            ldacc += inside ? ld : 0.f;
        }
    }
    sLDw[lane*5 + wave] = ldacc;
    __syncthreads();

    // ---- phase 5: log_det reduction across waves ----
    if (tid < 64) {
        float sld = sLDw[tid*5 + 0] + sLDw[tid*5 + 1]
                  + sLDw[tid*5 + 2] + sLDw[tid*5 + 3];
        ldout[row0 + tid] = sld;
    }
}

extern "C" void kernel_launch(void* const* d_in, const int* in_sizes, int n_in,
                              void* d_out, int out_size, void* d_ws, size_t ws_size,
                              hipStream_t stream)
{
    const float* x1 = (const float*)d_in[0];
    const float* x2 = (const float*)d_in[1];
    const float* W1 = (const float*)d_in[2];
    const float* b1 = (const float*)d_in[3];
    const float* W2 = (const float*)d_in[4];
    const float* b2 = (const float*)d_in[5];
    const float* W3 = (const float*)d_in[6];
    const float* b3 = (const float*)d_in[7];

    // d_ws layout (1,204,224 B total)
    ushort* W3T = (ushort*)d_ws;                 // 2048*256 fp16 = 1 MB
    ushort* W2T = W3T + 2048 * 256;              // 256*256 fp16
    ushort* W1T = W2T + 256 * 256;               // 256*32 fp16
    float*  b3p = (float*)(W1T + 256 * 32);      // 2048 f32

    float* zout  = (float*)d_out;                // (65536, 32)
    float* ldout = zout + (size_t)65536 * 32;    // (65536,)

    cvt_weights<<<876, 256, 0, stream>>>(W1, W2, W3, b3, W3T, W2T, W1T, b3p);
    rq_mfma<<<1024, 256, 0, stream>>>(x1, x2, b1, b2, W1T, W2T, W3T, b3p, zout, ldout);
}

// Round 13
// 212.604 us; speedup vs baseline: 1.6163x; 1.0951x over previous
//
#include <hip/hip_runtime.h>
#include <cmath>

#define NB 16
#define TAILV 3.0f
#define MINV 0.001f
#define CSC 0.984f   // 1 - NB*MINV

typedef __attribute__((ext_vector_type(8))) _Float16 half8;
typedef __attribute__((ext_vector_type(4))) float f32x4;

#define MFMA16(a,b,c) __builtin_amdgcn_mfma_f32_16x16x32_f16(a,b,c,0,0,0)

__device__ __forceinline__ ushort f2h(float f) {
    union { _Float16 h; ushort u; } v; v.h = (_Float16)f; return v.u;
}
__device__ __forceinline__ float softplus_f(float x) {
    return (x > 20.0f) ? x : __logf(1.0f + __expf(x));   // fast-math: margin absorbs ~ulp error
}

// ---- prologue: convert/transpose weights into d_ws (fp16, [N][K]) ----
// r13 TIGHT W3T layout (1600 rows, 22% smaller than the 2048 padded one):
//   rows [0,1536):    n = dim*48 + p   for p<48  (W 0-15 | H 16-31 | D 0-15)
//   rows [1536,1568): n = 1536 + dim   = d16 (17th derivative) per dim
//   rows [1568,1600): never read
// W2T: [256][256].  W1T: [256][32].  b3p mirrors the W3T n-mapping.
__global__ void __launch_bounds__(256)
cvt_weights(const float* __restrict__ W1, const float* __restrict__ W2,
            const float* __restrict__ W3, const float* __restrict__ b3,
            ushort* __restrict__ W3T, ushort* __restrict__ W2T,
            ushort* __restrict__ W1T, float* __restrict__ b3p)
{
    __shared__ float sm[64][65];
    const int b = blockIdx.x, t = threadIdx.x;
    const int tx = t & 63, ty = t >> 6;

    if (b < 100) {
        const int kt = b / 25, ct = b % 25;
        const int c = ct * 64 + tx;
        #pragma unroll
        for (int i = 0; i < 16; ++i) {
            const int k = kt * 64 + ty * 16 + i;
            float v = (c < 1568) ? W3[(size_t)k * 1568 + c] : 0.0f;
            sm[tx][ty * 16 + i] = v;               // sm[c_local][k_local]
        }
        __syncthreads();
        #pragma unroll
        for (int i = 0; i < 16; ++i) {
            const int clocal = ty * 16 + i;
            const int cc = ct * 64 + clocal;
            if (cc < 1568) {
                const int dim = cc / 49;
                const int p   = cc - dim * 49;
                const int n   = (p < 48) ? (dim * 48 + p) : (1536 + dim);
                W3T[(size_t)n * 256 + kt * 64 + tx] = f2h(sm[clocal][tx]);
            }
        }
    } else if (b < 107) {        // b3p (7 blocks cover n in [0,1792))
        const int n = (b - 100) * 256 + t;
        if (n < 1536) {
            const int dim = n / 48, p = n - dim * 48;
            b3p[n] = b3[dim * 49 + p];
        } else if (n < 1568) {
            b3p[n] = b3[(n - 1536) * 49 + 48];
        } else if (n < 1600) {
            b3p[n] = 0.0f;
        }
    } else if (b < 363) {        // W2T
        const int n = b - 107;
        W2T[(size_t)n * 256 + t] = f2h(W2[(size_t)t * 256 + n]);
    } else {                     // W1T (32 blocks, 8192 elems)
        const int idx = (b - 363) * 256 + t;
        const int n = idx >> 5, k = idx & 31;
        W1T[idx] = f2h(W1[(size_t)k * 256 + n]);
    }
}

// ---- fused main kernel: 64 batch rows / block, 4 waves, 1024 blocks ----
// r13 = r12 + tight GEMM3: 3 nt-tiles per dim (48 real cols, no store
// guard) + ONE d16 tile per wave per block (replaces 8 waste tiles).
// MFMA/wave 1024->800 (-22%), W3T bytes -22% (first actual work cut on
// the load->MFMA critical path; all prior rounds only reorganized it).
// P is [64][56]: cols 0-47 per-chunk, cols 48-55 persistent d16 per dim.
extern "C" __global__ void __launch_bounds__(256, 2)
rq_mfma(const float* __restrict__ x1, const float* __restrict__ x2,
        const float* __restrict__ b1, const float* __restrict__ b2,
        const ushort* __restrict__ W1T, const ushort* __restrict__ W2T,
        const ushort* __restrict__ W3T, const float* __restrict__ b3p,
        float* __restrict__ zout, float* __restrict__ ldout)
{
    __shared__ char smem[67072];
    float*  sX2  = (float*)smem;                    // [64][33] f32 = 8448
    float*  sLDw = (float*)(smem + 8448);           // [64][5] f32 = 1280
    char*   U    = smem + 9728;                     // 57344-byte union
    ushort* R0   = (ushort*)U;                      // [32][264] fp16 = 16896
    ushort* R1   = (ushort*)(U + 16896);            // [32][264]
    ushort* R2   = (ushort*)(U + 33792);            // [32][264]
    ushort* sA1  = R2;                              // [64][40] fp16 = 5120
    float*  sPw  = (float*)U;                       // 4 waves x [64][56] f32 = 57344

    const int tid  = threadIdx.x;
    const int row0 = blockIdx.x * 64;
    const int rot  = blockIdx.x & 7;
    const int wave = tid >> 6, lane = tid & 63;
    const int ln = lane & 15, kg = lane >> 4;       // frag: m/n=ln, k-group=kg

    // ---- phase 0: stage x1 (->fp16, R2) and x2 (f32) ----
    {
        int r = tid >> 2, c = (tid & 3) << 3;
        float4 v0 = *(const float4*)(x1 + (size_t)(row0 + r) * 32 + c);
        float4 v1 = *(const float4*)(x1 + (size_t)(row0 + r) * 32 + c + 4);
        sA1[r*40 + c    ] = f2h(v0.x); sA1[r*40 + c + 1] = f2h(v0.y);
        sA1[r*40 + c + 2] = f2h(v0.z); sA1[r*40 + c + 3] = f2h(v0.w);
        sA1[r*40 + c + 4] = f2h(v1.x); sA1[r*40 + c + 5] = f2h(v1.y);
        sA1[r*40 + c + 6] = f2h(v1.z); sA1[r*40 + c + 7] = f2h(v1.w);
        float4 w0 = *(const float4*)(x2 + (size_t)(row0 + r) * 32 + c);
        float4 w1 = *(const float4*)(x2 + (size_t)(row0 + r) * 32 + c + 4);
        sX2[r*33 + c    ] = w0.x; sX2[r*33 + c + 1] = w0.y;
        sX2[r*33 + c + 2] = w0.z; sX2[r*33 + c + 3] = w0.w;
        sX2[r*33 + c + 4] = w1.x; sX2[r*33 + c + 5] = w1.y;
        sX2[r*33 + c + 6] = w1.z; sX2[r*33 + c + 7] = w1.w;
    }
    __syncthreads();

    // ---- phase 1: h1 = relu(x1 @ W1 + b1); 4 M-tiles, K=32 ----
    {
        half8 a[4];
        #pragma unroll
        for (int m = 0; m < 4; ++m)
            a[m] = *(const half8*)(sA1 + (m*16 + ln)*40 + kg*8);
        #pragma unroll
        for (int nt = 0; nt < 4; ++nt) {
            int n = wave*64 + nt*16 + ln;
            half8 bfr = *(const half8*)(W1T + n*32 + kg*8);
            float bias = b1[n];
            f32x4 zr = {0.f,0.f,0.f,0.f};
            #pragma unroll
            for (int m = 0; m < 4; ++m) {
                f32x4 cm = MFMA16(a[m], bfr, zr);
                ushort* dst = (m < 2) ? R0 : R1;
                int rb = (m & 1) * 16;
                #pragma unroll
                for (int g = 0; g < 4; ++g)
                    dst[(rb + kg*4 + g)*264 + n] = f2h(fmaxf(cm[g] + bias, 0.f));
            }
        }
    }
    __syncthreads();

    // ---- phase 2: h2 = relu(h1 @ W2 + b2), two 32-row half-passes ----
    #pragma unroll
    for (int part = 0; part < 2; ++part) {
        const ushort* S = (part == 0) ? R0 : R1;   // h1 rows
        ushort*       D = (part == 0) ? R2 : R0;   // h2 rows
        half8 a0[8], a1[8];
        #pragma unroll
        for (int ks = 0; ks < 8; ++ks) {
            a0[ks] = *(const half8*)(S + ln*264 + ks*32 + kg*8);
            a1[ks] = *(const half8*)(S + (16 + ln)*264 + ks*32 + kg*8);
        }
        #pragma unroll
        for (int nt = 0; nt < 4; ++nt) {
            int n = wave*64 + nt*16 + ln;
            f32x4 c0 = {0,0,0,0}, c1 = {0,0,0,0};
            const ushort* bp = W2T + (size_t)n*256 + kg*8;
            #pragma unroll
            for (int ks = 0; ks < 8; ++ks) {
                half8 bfr = *(const half8*)(bp + ks*32);
                c0 = MFMA16(a0[ks], bfr, c0);
                c1 = MFMA16(a1[ks], bfr, c1);
            }
            float bias = b2[n];
            #pragma unroll
            for (int g = 0; g < 4; ++g) {
                D[(kg*4 + g)*264 + n]      = f2h(fmaxf(c0[g] + bias, 0.f));
                D[(16 + kg*4 + g)*264 + n] = f2h(fmaxf(c1[g] + bias, 0.f));
            }
        }
        __syncthreads();
    }

    // ---- phase 3: hoist GEMM3 A-fragments (4 M-tiles x 8 ks = 128 regs) ----
    half8 A[4][8];
    #pragma unroll
    for (int m = 0; m < 4; ++m) {
        const ushort* src = (m < 2) ? R2 : R0;     // h2 rows 0-31 / 32-63
        int rb = (m & 1) * 16;
        #pragma unroll
        for (int ks = 0; ks < 8; ++ks)
            A[m][ks] = *(const half8*)(src + (rb + ln)*264 + ks*32 + kg*8);
    }
    __syncthreads();   // staging dead; sPw overlays U

    // ---- phase 4: GEMM3 + fused spline; wave owns dims [wave*8, wave*8+8) ----
    float* myP = sPw + wave * (64 * 56);           // [64][56] f32
    float  ldacc = 0.f;

    // prologue A: d16 tile — 16 cols = d16 of dims [(wave>>1)*16, +16);
    // this wave stores the 8 it owns into persistent cols 48..55 of myP.
    {
        const int ebase = 1536 + (wave >> 1) * 16;
        const ushort* bp = W3T + (size_t)(ebase + ln) * 256 + kg*8;
        half8 be[8];
        #pragma unroll
        for (int ks = 0; ks < 8; ++ks) be[ks] = *(const half8*)(bp + ks*32);
        const float biasE = b3p[ebase + ln];
        f32x4 c[4];
        #pragma unroll
        for (int m = 0; m < 4; ++m) c[m] = (f32x4){0,0,0,0};
        #pragma unroll
        for (int ks = 0; ks < 8; ++ks)
            #pragma unroll
            for (int m = 0; m < 4; ++m)
                c[m] = MFMA16(A[m][ks], be[ks], c[m]);
        if ((ln >> 3) == (wave & 1)) {             // lane's dim owned by this wave
            const int j = ln & 7;
            #pragma unroll
            for (int m = 0; m < 4; ++m)
                #pragma unroll
                for (int g = 0; g < 4; ++g)
                    myP[(m*16 + kg*4 + g)*56 + 48 + j] = c[m][g] + biasE;
        }
    }

    // prologue B: first chunk's first B-tile
    half8 bcur[8], bnxt[8];
    {
        int dim0 = wave*8 + rot;
        const ushort* bp = W3T + (size_t)(dim0*48 + ln)*256 + kg*8;
        #pragma unroll
        for (int ks = 0; ks < 8; ++ks) bcur[ks] = *(const half8*)(bp + ks*32);
    }

    for (int ch0 = 0; ch0 < 8; ++ch0) {
        const int dim = wave*8 + ((ch0 + rot) & 7);
        float bias[3];
        #pragma unroll
        for (int nt = 0; nt < 3; ++nt) bias[nt] = b3p[dim*48 + nt*16 + ln];

        #pragma unroll
        for (int nt = 0; nt < 3; ++nt) {
            const bool last = (ch0 == 7) && (nt == 2);
            if (!last) {   // prefetch next tile (rotated order)
                int ndim = (nt == 2) ? (wave*8 + ((ch0 + 1 + rot) & 7)) : dim;
                int nnt  = (nt == 2) ? 0 : nt + 1;
                const ushort* bp = W3T + (size_t)(ndim*48 + nnt*16 + ln)*256 + kg*8;
                #pragma unroll
                for (int ks = 0; ks < 8; ++ks) bnxt[ks] = *(const half8*)(bp + ks*32);
            }
            f32x4 c[4];
            #pragma unroll
            for (int m = 0; m < 4; ++m) c[m] = (f32x4){0,0,0,0};
            #pragma unroll
            for (int ks = 0; ks < 8; ++ks)
                #pragma unroll
                for (int m = 0; m < 4; ++m)
                    c[m] = MFMA16(A[m][ks], bcur[ks], c[m]);
            const int p = nt*16 + ln;              // < 48: every lane real
            #pragma unroll
            for (int m = 0; m < 4; ++m)
                #pragma unroll
                for (int g = 0; g < 4; ++g)
                    myP[(m*16 + kg*4 + g)*56 + p] = c[m][g] + bias[nt];
            if (!last) {
                #pragma unroll
                for (int ks = 0; ks < 8; ++ks) bcur[ks] = bnxt[ks];
            }
        }

        // spline: r12-verified body; stride 52->56, d16 col select for d1.
        {
            const float* myPl = myP + lane * 56;
            const f32x4* pr   = (const f32x4*)myPl;
            const float x  = sX2[lane*33 + dim];
            const float xc = fminf(fmaxf(x, -TAILV), TAILV);

            f32x4 Lw[4], Lh[4];
            #pragma unroll
            for (int q = 0; q < 4; ++q) Lw[q] = pr[q];       // p 0..15
            #pragma unroll
            for (int q = 0; q < 4; ++q) Lh[q] = pr[4 + q];   // p 16..31

            float e[NB];
            #pragma unroll
            for (int k = 0; k < NB; ++k) e[k] = __expf(Lw[k>>2][k&3]);
            float s;
            {
                float a0=e[0]+e[1],   a1=e[2]+e[3],   a2=e[4]+e[5],   a3=e[6]+e[7];
                float a4=e[8]+e[9],   a5=e[10]+e[11], a6=e[12]+e[13], a7=e[14]+e[15];
                s = ((a0+a1)+(a2+a3)) + ((a4+a5)+(a6+a7));
            }
            const float inv = 1.f / s;

            int idx = 0; float xk = -TAILV, xk1 = TAILV; float cum = 0.f;
            #pragma unroll
            for (int k = 0; k < NB; ++k) {
                float lo = -TAILV + 2.f * TAILV * cum;
                cum += MINV + CSC * e[k] * inv;
                float hi = -TAILV + 2.f * TAILV * cum;
                if (lo <= xc) { idx = k; xk = lo; xk1 = hi; }
            }

            float eh[NB];
            #pragma unroll
            for (int k = 0; k < NB; ++k) eh[k] = __expf(Lh[k>>2][k&3]);
            float sh;
            {
                float a0=eh[0]+eh[1],   a1=eh[2]+eh[3],   a2=eh[4]+eh[5],   a3=eh[6]+eh[7];
                float a4=eh[8]+eh[9],   a5=eh[10]+eh[11], a6=eh[12]+eh[13], a7=eh[14]+eh[15];
                sh = ((a0+a1)+(a2+a3)) + ((a4+a5)+(a6+a7));
            }
            const float invh = 1.f / sh;

            float yk = -TAILV, yk1 = TAILV; cum = 0.f;
            #pragma unroll
            for (int k = 0; k < NB; ++k) {
                float lo = -TAILV + 2.f * TAILV * cum;
                cum += MINV + CSC * eh[k] * invh;
                float hi = -TAILV + 2.f * TAILV * cum;
                if (k == idx) { yk = lo; yk1 = hi; }
            }

            const float d0 = MINV + softplus_f(myPl[32 + idx]);
            const int   i1 = (idx < 15) ? (33 + idx) : (48 + (dim & 7));
            const float d1 = MINV + softplus_f(myPl[i1]);

            const float wd = xk1 - xk, hd = yk1 - yk;
            const float sk = hd / wd;
            const float xi = (xc - xk) / wd;
            const float xim = xi * (1.f - xi);
            const float alpha = hd * (sk * xi * xi + d0 * xim);
            const float beta  = sk + (d1 + d0 - 2.f * sk) * xim;
            const float z     = yk + alpha / beta;
            const float om    = 1.f - xi;
            const float dn    = sk * sk * (d1 * xi * xi + 2.f * sk * xim + d0 * om * om);
            const float ld    = __logf(dn / (beta * beta));

            const bool inside = (x >= -TAILV) && (x <= TAILV);
            zout[(size_t)(row0 + lane) * 32 + dim] = inside ? z : x;
            ldacc += inside ? ld : 0.f;
        }
    }
    sLDw[lane*5 + wave] = ldacc;
    __syncthreads();

    // ---- phase 5: log_det reduction across waves ----
    if (tid < 64) {
        float sld = sLDw[tid*5 + 0] + sLDw[tid*5 + 1]
                  + sLDw[tid*5 + 2] + sLDw[tid*5 + 3];
        ldout[row0 + tid] = sld;
    }
}

extern "C" void kernel_launch(void* const* d_in, const int* in_sizes, int n_in,
                              void* d_out, int out_size, void* d_ws, size_t ws_size,
                              hipStream_t stream)
{
    const float* x1 = (const float*)d_in[0];
    const float* x2 = (const float*)d_in[1];
    const float* W1 = (const float*)d_in[2];
    const float* b1 = (const float*)d_in[3];
    const float* W2 = (const float*)d_in[4];
    const float* b2 = (const float*)d_in[5];
    const float* W3 = (const float*)d_in[6];
    const float* b3 = (const float*)d_in[7];

    // d_ws layout (region offsets kept from prior rounds; W3T now uses
    // only 1600 of its 2048 rows)
    ushort* W3T = (ushort*)d_ws;                 // 1600*256 fp16 used
    ushort* W2T = W3T + 2048 * 256;              // 256*256 fp16
    ushort* W1T = W2T + 256 * 256;               // 256*32 fp16
    float*  b3p = (float*)(W1T + 256 * 32);      // 1600 f32 used

    float* zout  = (float*)d_out;                // (65536, 32)
    float* ldout = zout + (size_t)65536 * 32;    // (65536,)

    cvt_weights<<<395, 256, 0, stream>>>(W1, W2, W3, b3, W3T, W2T, W1T, b3p);
    rq_mfma<<<1024, 256, 0, stream>>>(x1, x2, b1, b2, W1T, W2T, W3T, b3p, zout, ldout);
}

// Round 14
// 211.418 us; speedup vs baseline: 1.6254x; 1.0056x over previous
//
#include <hip/hip_runtime.h>
#include <cmath>

#define NB 16
#define TAILV 3.0f
#define MINV 0.001f
#define CSC 0.984f   // 1 - NB*MINV
#define PSTR 60      // P row stride (f32): 60 mod 32 = 28, gcd 4 -> 8 bank groups

typedef __attribute__((ext_vector_type(8))) _Float16 half8;
typedef __attribute__((ext_vector_type(4))) float f32x4;

#define MFMA16(a,b,c) __builtin_amdgcn_mfma_f32_16x16x32_f16(a,b,c,0,0,0)

__device__ __forceinline__ ushort f2h(float f) {
    union { _Float16 h; ushort u; } v; v.h = (_Float16)f; return v.u;
}
__device__ __forceinline__ float softplus_f(float x) {
    return (x > 20.0f) ? x : __logf(1.0f + __expf(x));   // fast-math: margin absorbs ~ulp error
}

// ---- prologue: convert/transpose weights into d_ws (fp16, [N][K]) ----
// TIGHT W3T layout (1600 rows):
//   rows [0,1536):    n = dim*48 + p   for p<48  (W 0-15 | H 16-31 | D 0-15)
//   rows [1536,1568): n = 1536 + dim   = d16 (17th derivative) per dim
// W2T: [256][256].  W1T: [256][32].  b3p mirrors the W3T n-mapping.
__global__ void __launch_bounds__(256)
cvt_weights(const float* __restrict__ W1, const float* __restrict__ W2,
            const float* __restrict__ W3, const float* __restrict__ b3,
            ushort* __restrict__ W3T, ushort* __restrict__ W2T,
            ushort* __restrict__ W1T, float* __restrict__ b3p)
{
    __shared__ float sm[64][65];
    const int b = blockIdx.x, t = threadIdx.x;
    const int tx = t & 63, ty = t >> 6;

    if (b < 100) {
        const int kt = b / 25, ct = b % 25;
        const int c = ct * 64 + tx;
        #pragma unroll
        for (int i = 0; i < 16; ++i) {
            const int k = kt * 64 + ty * 16 + i;
            float v = (c < 1568) ? W3[(size_t)k * 1568 + c] : 0.0f;
            sm[tx][ty * 16 + i] = v;               // sm[c_local][k_local]
        }
        __syncthreads();
        #pragma unroll
        for (int i = 0; i < 16; ++i) {
            const int clocal = ty * 16 + i;
            const int cc = ct * 64 + clocal;
            if (cc < 1568) {
                const int dim = cc / 49;
                const int p   = cc - dim * 49;
                const int n   = (p < 48) ? (dim * 48 + p) : (1536 + dim);
                W3T[(size_t)n * 256 + kt * 64 + tx] = f2h(sm[clocal][tx]);
            }
        }
    } else if (b < 107) {        // b3p (7 blocks cover n in [0,1792))
        const int n = (b - 100) * 256 + t;
        if (n < 1536) {
            const int dim = n / 48, p = n - dim * 48;
            b3p[n] = b3[dim * 49 + p];
        } else if (n < 1568) {
            b3p[n] = b3[(n - 1536) * 49 + 48];
        } else if (n < 1600) {
            b3p[n] = 0.0f;
        }
    } else if (b < 363) {        // W2T
        const int n = b - 107;
        W2T[(size_t)n * 256 + t] = f2h(W2[(size_t)t * 256 + n]);
    } else {                     // W1T (32 blocks, 8192 elems)
        const int idx = (b - 363) * 256 + t;
        const int n = idx >> 5, k = idx & 31;
        W1T[idx] = f2h(W1[(size_t)k * 256 + n]);
    }
}

// ---- fused main kernel: 64 batch rows / block, 4 waves, 1024 blocks ----
// r14 = r13 (verified 149.5us; tight GEMM3, -22% B-path work) + two fixes:
//   (1) P stride 56->60: restores gcd-4 bank spread (r13's 56 had gcd 8,
//       conflicts 1.46M->5.8M); 16B alignment kept (240B rows).
//   (2) d16 prologue reuses bnxt[] for its B-tile (was separate be[8],
//       +32 regs peak -> small scratch spill, WRITE_SIZE +3.2MB).
extern "C" __global__ void __launch_bounds__(256, 2)
rq_mfma(const float* __restrict__ x1, const float* __restrict__ x2,
        const float* __restrict__ b1, const float* __restrict__ b2,
        const ushort* __restrict__ W1T, const ushort* __restrict__ W2T,
        const ushort* __restrict__ W3T, const float* __restrict__ b3p,
        float* __restrict__ zout, float* __restrict__ ldout)
{
    __shared__ char smem[71168];
    float*  sX2  = (float*)smem;                    // [64][33] f32 = 8448
    float*  sLDw = (float*)(smem + 8448);           // [64][5] f32 = 1280
    char*   U    = smem + 9728;                     // 61440-byte union
    ushort* R0   = (ushort*)U;                      // [32][264] fp16 = 16896
    ushort* R1   = (ushort*)(U + 16896);            // [32][264]
    ushort* R2   = (ushort*)(U + 33792);            // [32][264]
    ushort* sA1  = R2;                              // [64][40] fp16 = 5120
    float*  sPw  = (float*)U;                       // 4 waves x [64][60] f32 = 61440

    const int tid  = threadIdx.x;
    const int row0 = blockIdx.x * 64;
    const int rot  = blockIdx.x & 7;
    const int wave = tid >> 6, lane = tid & 63;
    const int ln = lane & 15, kg = lane >> 4;       // frag: m/n=ln, k-group=kg

    // ---- phase 0: stage x1 (->fp16, R2) and x2 (f32) ----
    {
        int r = tid >> 2, c = (tid & 3) << 3;
        float4 v0 = *(const float4*)(x1 + (size_t)(row0 + r) * 32 + c);
        float4 v1 = *(const float4*)(x1 + (size_t)(row0 + r) * 32 + c + 4);
        sA1[r*40 + c    ] = f2h(v0.x); sA1[r*40 + c + 1] = f2h(v0.y);
        sA1[r*40 + c + 2] = f2h(v0.z); sA1[r*40 + c + 3] = f2h(v0.w);
        sA1[r*40 + c + 4] = f2h(v1.x); sA1[r*40 + c + 5] = f2h(v1.y);
        sA1[r*40 + c + 6] = f2h(v1.z); sA1[r*40 + c + 7] = f2h(v1.w);
        float4 w0 = *(const float4*)(x2 + (size_t)(row0 + r) * 32 + c);
        float4 w1 = *(const float4*)(x2 + (size_t)(row0 + r) * 32 + c + 4);
        sX2[r*33 + c    ] = w0.x; sX2[r*33 + c + 1] = w0.y;
        sX2[r*33 + c + 2] = w0.z; sX2[r*33 + c + 3] = w0.w;
        sX2[r*33 + c + 4] = w1.x; sX2[r*33 + c + 5] = w1.y;
        sX2[r*33 + c + 6] = w1.z; sX2[r*33 + c + 7] = w1.w;
    }
    __syncthreads();

    // ---- phase 1: h1 = relu(x1 @ W1 + b1); 4 M-tiles, K=32 ----
    {
        half8 a[4];
        #pragma unroll
        for (int m = 0; m < 4; ++m)
            a[m] = *(const half8*)(sA1 + (m*16 + ln)*40 + kg*8);
        #pragma unroll
        for (int nt = 0; nt < 4; ++nt) {
            int n = wave*64 + nt*16 + ln;
            half8 bfr = *(const half8*)(W1T + n*32 + kg*8);
            float bias = b1[n];
            f32x4 zr = {0.f,0.f,0.f,0.f};
            #pragma unroll
            for (int m = 0; m < 4; ++m) {
                f32x4 cm = MFMA16(a[m], bfr, zr);
                ushort* dst = (m < 2) ? R0 : R1;
                int rb = (m & 1) * 16;
                #pragma unroll
                for (int g = 0; g < 4; ++g)
                    dst[(rb + kg*4 + g)*264 + n] = f2h(fmaxf(cm[g] + bias, 0.f));
            }
        }
    }
    __syncthreads();

    // ---- phase 2: h2 = relu(h1 @ W2 + b2), two 32-row half-passes ----
    #pragma unroll
    for (int part = 0; part < 2; ++part) {
        const ushort* S = (part == 0) ? R0 : R1;   // h1 rows
        ushort*       D = (part == 0) ? R2 : R0;   // h2 rows
        half8 a0[8], a1[8];
        #pragma unroll
        for (int ks = 0; ks < 8; ++ks) {
            a0[ks] = *(const half8*)(S + ln*264 + ks*32 + kg*8);
            a1[ks] = *(const half8*)(S + (16 + ln)*264 + ks*32 + kg*8);
        }
        #pragma unroll
        for (int nt = 0; nt < 4; ++nt) {
            int n = wave*64 + nt*16 + ln;
            f32x4 c0 = {0,0,0,0}, c1 = {0,0,0,0};
            const ushort* bp = W2T + (size_t)n*256 + kg*8;
            #pragma unroll
            for (int ks = 0; ks < 8; ++ks) {
                half8 bfr = *(const half8*)(bp + ks*32);
                c0 = MFMA16(a0[ks], bfr, c0);
                c1 = MFMA16(a1[ks], bfr, c1);
            }
            float bias = b2[n];
            #pragma unroll
            for (int g = 0; g < 4; ++g) {
                D[(kg*4 + g)*264 + n]      = f2h(fmaxf(c0[g] + bias, 0.f));
                D[(16 + kg*4 + g)*264 + n] = f2h(fmaxf(c1[g] + bias, 0.f));
            }
        }
        __syncthreads();
    }

    // ---- phase 3: hoist GEMM3 A-fragments (4 M-tiles x 8 ks = 128 regs) ----
    half8 A[4][8];
    #pragma unroll
    for (int m = 0; m < 4; ++m) {
        const ushort* src = (m < 2) ? R2 : R0;     // h2 rows 0-31 / 32-63
        int rb = (m & 1) * 16;
        #pragma unroll
        for (int ks = 0; ks < 8; ++ks)
            A[m][ks] = *(const half8*)(src + (rb + ln)*264 + ks*32 + kg*8);
    }
    __syncthreads();   // staging dead; sPw overlays U

    // ---- phase 4: GEMM3 + fused spline; wave owns dims [wave*8, wave*8+8) ----
    float* myP = sPw + wave * (64 * PSTR);         // [64][60] f32
    float  ldacc = 0.f;

    half8 bcur[8], bnxt[8];

    // prologue A: d16 tile — 16 cols = d16 of dims [(wave>>1)*16, +16);
    // B-tile staged in bnxt (no separate be[] -> no extra reg pressure);
    // this wave stores the 8 dims it owns into persistent cols 48..55.
    {
        const int ebase = 1536 + (wave >> 1) * 16;
        const ushort* bp = W3T + (size_t)(ebase + ln) * 256 + kg*8;
        #pragma unroll
        for (int ks = 0; ks < 8; ++ks) bnxt[ks] = *(const half8*)(bp + ks*32);
        const float biasE = b3p[ebase + ln];
        f32x4 c[4];
        #pragma unroll
        for (int m = 0; m < 4; ++m) c[m] = (f32x4){0,0,0,0};
        #pragma unroll
        for (int ks = 0; ks < 8; ++ks)
            #pragma unroll
            for (int m = 0; m < 4; ++m)
                c[m] = MFMA16(A[m][ks], bnxt[ks], c[m]);
        if ((ln >> 3) == (wave & 1)) {             // lane's dim owned by this wave
            const int j = ln & 7;
            #pragma unroll
            for (int m = 0; m < 4; ++m)
                #pragma unroll
                for (int g = 0; g < 4; ++g)
                    myP[(m*16 + kg*4 + g)*PSTR + 48 + j] = c[m][g] + biasE;
        }
    }

    // prologue B: first chunk's first B-tile
    {
        int dim0 = wave*8 + rot;
        const ushort* bp = W3T + (size_t)(dim0*48 + ln)*256 + kg*8;
        #pragma unroll
        for (int ks = 0; ks < 8; ++ks) bcur[ks] = *(const half8*)(bp + ks*32);
    }

    for (int ch0 = 0; ch0 < 8; ++ch0) {
        const int dim = wave*8 + ((ch0 + rot) & 7);
        float bias[3];
        #pragma unroll
        for (int nt = 0; nt < 3; ++nt) bias[nt] = b3p[dim*48 + nt*16 + ln];

        #pragma unroll
        for (int nt = 0; nt < 3; ++nt) {
            const bool last = (ch0 == 7) && (nt == 2);
            if (!last) {   // prefetch next tile (rotated order)
                int ndim = (nt == 2) ? (wave*8 + ((ch0 + 1 + rot) & 7)) : dim;
                int nnt  = (nt == 2) ? 0 : nt + 1;
                const ushort* bp = W3T + (size_t)(ndim*48 + nnt*16 + ln)*256 + kg*8;
                #pragma unroll
                for (int ks = 0; ks < 8; ++ks) bnxt[ks] = *(const half8*)(bp + ks*32);
            }
            f32x4 c[4];
            #pragma unroll
            for (int m = 0; m < 4; ++m) c[m] = (f32x4){0,0,0,0};
            #pragma unroll
            for (int ks = 0; ks < 8; ++ks)
                #pragma unroll
                for (int m = 0; m < 4; ++m)
                    c[m] = MFMA16(A[m][ks], bcur[ks], c[m]);
            const int p = nt*16 + ln;              // < 48: every lane real
            #pragma unroll
            for (int m = 0; m < 4; ++m)
                #pragma unroll
                for (int g = 0; g < 4; ++g)
                    myP[(m*16 + kg*4 + g)*PSTR + p] = c[m][g] + bias[nt];
            if (!last) {
                #pragma unroll
                for (int ks = 0; ks < 8; ++ks) bcur[ks] = bnxt[ks];
            }
        }

        // spline: r12-verified body; stride PSTR, d16 col select for d1.
        {
            const float* myPl = myP + lane * PSTR;
            const f32x4* pr   = (const f32x4*)myPl;
            const float x  = sX2[lane*33 + dim];
            const float xc = fminf(fmaxf(x, -TAILV), TAILV);

            f32x4 Lw[4], Lh[4];
            #pragma unroll
            for (int q = 0; q < 4; ++q) Lw[q] = pr[q];       // p 0..15
            #pragma unroll
            for (int q = 0; q < 4; ++q) Lh[q] = pr[4 + q];   // p 16..31

            float e[NB];
            #pragma unroll
            for (int k = 0; k < NB; ++k) e[k] = __expf(Lw[k>>2][k&3]);
            float s;
            {
                float a0=e[0]+e[1],   a1=e[2]+e[3],   a2=e[4]+e[5],   a3=e[6]+e[7];
                float a4=e[8]+e[9],   a5=e[10]+e[11], a6=e[12]+e[13], a7=e[14]+e[15];
                s = ((a0+a1)+(a2+a3)) + ((a4+a5)+(a6+a7));
            }
            const float inv = 1.f / s;

            int idx = 0; float xk = -TAILV, xk1 = TAILV; float cum = 0.f;
            #pragma unroll
            for (int k = 0; k < NB; ++k) {
                float lo = -TAILV + 2.f * TAILV * cum;
                cum += MINV + CSC * e[k] * inv;
                float hi = -TAILV + 2.f * TAILV * cum;
                if (lo <= xc) { idx = k; xk = lo; xk1 = hi; }
            }

            float eh[NB];
            #pragma unroll
            for (int k = 0; k < NB; ++k) eh[k] = __expf(Lh[k>>2][k&3]);
            float sh;
            {
                float a0=eh[0]+eh[1],   a1=eh[2]+eh[3],   a2=eh[4]+eh[5],   a3=eh[6]+eh[7];
                float a4=eh[8]+eh[9],   a5=eh[10]+eh[11], a6=eh[12]+eh[13], a7=eh[14]+eh[15];
                sh = ((a0+a1)+(a2+a3)) + ((a4+a5)+(a6+a7));
            }
            const float invh = 1.f / sh;

            float yk = -TAILV, yk1 = TAILV; cum = 0.f;
            #pragma unroll
            for (int k = 0; k < NB; ++k) {
                float lo = -TAILV + 2.f * TAILV * cum;
                cum += MINV + CSC * eh[k] * invh;
                float hi = -TAILV + 2.f * TAILV * cum;
                if (k == idx) { yk = lo; yk1 = hi; }
            }

            const float d0 = MINV + softplus_f(myPl[32 + idx]);
            const int   i1 = (idx < 15) ? (33 + idx) : (48 + (dim & 7));
            const float d1 = MINV + softplus_f(myPl[i1]);

            const float wd = xk1 - xk, hd = yk1 - yk;
            const float sk = hd / wd;
            const float xi = (xc - xk) / wd;
            const float xim = xi * (1.f - xi);
            const float alpha = hd * (sk * xi * xi + d0 * xim);
            const float beta  = sk + (d1 + d0 - 2.f * sk) * xim;
            const float z     = yk + alpha / beta;
            const float om    = 1.f - xi;
            const float dn    = sk * sk * (d1 * xi * xi + 2.f * sk * xim + d0 * om * om);
            const float ld    = __logf(dn / (beta * beta));

            const bool inside = (x >= -TAILV) && (x <= TAILV);
            zout[(size_t)(row0 + lane) * 32 + dim] = inside ? z : x;
            ldacc += inside ? ld : 0.f;
        }
    }
    sLDw[lane*5 + wave] = ldacc;
    __syncthreads();

    // ---- phase 5: log_det reduction across waves ----
    if (tid < 64) {
        float sld = sLDw[tid*5 + 0] + sLDw[tid*5 + 1]
                  + sLDw[tid*5 + 2] + sLDw[tid*5 + 3];
        ldout[row0 + tid] = sld;
    }
}

extern "C" void kernel_launch(void* const* d_in, const int* in_sizes, int n_in,
                              void* d_out, int out_size, void* d_ws, size_t ws_size,
                              hipStream_t stream)
{
    const float* x1 = (const float*)d_in[0];
    const float* x2 = (const float*)d_in[1];
    const float* W1 = (const float*)d_in[2];
    const float* b1 = (const float*)d_in[3];
    const float* W2 = (const float*)d_in[4];
    const float* b2 = (const float*)d_in[5];
    const float* W3 = (const float*)d_in[6];
    const float* b3 = (const float*)d_in[7];

    // d_ws layout (region offsets kept; W3T uses 1600 of its 2048 rows)
    ushort* W3T = (ushort*)d_ws;                 // 1600*256 fp16 used
    ushort* W2T = W3T + 2048 * 256;              // 256*256 fp16
    ushort* W1T = W2T + 256 * 256;               // 256*32 fp16
    float*  b3p = (float*)(W1T + 256 * 32);      // 1600 f32 used

    float* zout  = (float*)d_out;                // (65536, 32)
    float* ldout = zout + (size_t)65536 * 32;    // (65536,)

    cvt_weights<<<395, 256, 0, stream>>>(W1, W2, W3, b3, W3T, W2T, W1T, b3p);
    rq_mfma<<<1024, 256, 0, stream>>>(x1, x2, b1, b2, W1T, W2T, W3T, b3p, zout, ldout);
}